// Round 5
// baseline (5428.410 us; speedup 1.0000x reference)
//
#include <hip/hip_runtime.h>

typedef unsigned short u16;
typedef unsigned int u32;

#define SEQn   2048
#define DMn    1024
#define NHn    16
#define DKn    64
#define BATCHn 2
#define MR     (BATCHn*SEQn)   // 4096 rows

__device__ __forceinline__ u16 f2bf(float f){
  u32 u = __builtin_bit_cast(u32, f);
  u32 r = (u + 0x7FFFu + ((u >> 16) & 1u)) >> 16;   // RNE
  return (u16)r;
}
__device__ __forceinline__ float bf2f(u32 b){ return __builtin_bit_cast(float, b << 16); }

// ---------------- RoPE in place on bf16 tensor [m][h][d], inline sincos ----------------
__global__ __launch_bounds__(256) void rope_kernel(u32* __restrict__ x, const int* __restrict__ pos){
  int p = blockIdx.x*256 + threadIdx.x;       // exact grid: MR*DMn/2 pairs
  int s = (p >> 9) & (SEQn - 1);
  int k = p & 31;
  float inv = powf(10000.0f, -(float)k * (1.0f/32.0f));   // theta^(-2k/64)
  float a = (float)pos[s] * inv;
  float sn, cs;
  sincosf(a, &sn, &cs);
  u32 u = x[p];
  float xe = bf2f(u & 0xffffu);
  float xo = bf2f(u >> 16);
  float re = xe*cs - xo*sn;
  float ro = xe*sn + xo*cs;
  x[p] = (u32)f2bf(re) | ((u32)f2bf(ro) << 16);
}

// ---------------- simple VALU f32 GEMM: C[M][1024] = A[M][1024] * W[1024][1024]^T ----------------
// 64x64 tile, 256 threads, 4x4 outputs per thread.
// AT: float (device inputs) or u16 (bf16 intermediate). CT: u16 (intermediate) or float (d_out).
template<typename AT, typename CT>
__global__ __launch_bounds__(256) void gemm_naive(const AT* __restrict__ A, const float* __restrict__ W,
                                                  CT* __restrict__ C){
  __shared__ float As[64][33];
  __shared__ float Ws[64][33];
  const int tid = threadIdx.x;
  const int m0 = blockIdx.y*64, n0 = blockIdx.x*64;
  const int tr = tid >> 4, tc = tid & 15;     // 16x16 thread grid, 4x4 each
  float acc[4][4] = {};
  const int sr = tid >> 2;                    // staging row 0..63
  const int sk = (tid & 3) * 8;               // staging k-offset {0,8,16,24}

  for (int kt = 0; kt < DMn; kt += 32){
    __syncthreads();
    if constexpr (sizeof(AT) == 2){
      const u16* ap = (const u16*)A + (size_t)(m0 + sr)*DMn + kt + sk;
#pragma unroll
      for (int e = 0; e < 8; e++) As[sr][sk + e] = bf2f(ap[e]);
    } else {
      const float* ap = (const float*)A + (size_t)(m0 + sr)*DMn + kt + sk;
#pragma unroll
      for (int e = 0; e < 8; e++) As[sr][sk + e] = ap[e];
    }
    {
      const float* wp = W + (size_t)(n0 + sr)*DMn + kt + sk;
#pragma unroll
      for (int e = 0; e < 8; e++) Ws[sr][sk + e] = wp[e];
    }
    __syncthreads();
#pragma unroll
    for (int kk = 0; kk < 32; kk++){
      float a[4], w[4];
#pragma unroll
      for (int x = 0; x < 4; x++){ a[x] = As[tr*4 + x][kk]; w[x] = Ws[tc*4 + x][kk]; }
#pragma unroll
      for (int x = 0; x < 4; x++)
#pragma unroll
        for (int y = 0; y < 4; y++) acc[x][y] = fmaf(a[x], w[y], acc[x][y]);
    }
  }
#pragma unroll
  for (int x = 0; x < 4; x++)
#pragma unroll
    for (int y = 0; y < 4; y++){
      if constexpr (sizeof(CT) == 2)
        C[(size_t)(m0 + tr*4 + x)*DMn + (n0 + tc*4 + y)] = f2bf(acc[x][y]);
      else
        C[(size_t)(m0 + tr*4 + x)*DMn + (n0 + tc*4 + y)] = acc[x][y];
    }
}

// ---------------- causal attention (proven bisection version) ----------------
// One WAVE per query. Exact loop bound k <= q, no masking arithmetic.
// Lane d owns feature d. Score via __shfl_xor wave reduction. f32 online softmax.
__global__ __launch_bounds__(256) void attn2_kernel(const u16* __restrict__ xq, const u16* __restrict__ xk,
                                                    const u16* __restrict__ xv, u16* __restrict__ xo){
  const int tid  = threadIdx.x;
  const int lane = tid & 63;
  const int w    = blockIdx.x*4 + (tid >> 6);   // global wave id, 0..65535
  const int q    = w & (SEQn - 1);
  const int bh   = w >> 11;                     // b*16 + h
  const int b    = bh >> 4, h = bh & 15;

  const size_t base = (size_t)b*SEQn*DMn + (size_t)h*DKn;   // row (b, s=0), head h
  const size_t qrow = base + (size_t)q*DMn;

  const float qf = bf2f(xq[qrow + lane]) * 0.125f;   // 1/sqrt(64)
  float of = 0.f, m = -3e38f, l = 0.f;

  for (int k = 0; k <= q; k++){
    const size_t kro = base + (size_t)k*DMn;
    float kv = bf2f(xk[kro + lane]);
    float sp = qf * kv;
    sp += __shfl_xor(sp, 1);
    sp += __shfl_xor(sp, 2);
    sp += __shfl_xor(sp, 4);
    sp += __shfl_xor(sp, 8);
    sp += __shfl_xor(sp, 16);
    sp += __shfl_xor(sp, 32);                  // full-wave sum, broadcast to all lanes
    float vv = bf2f(xv[kro + lane]);
    float mn = fmaxf(m, sp);
    float corr = __expf(m - mn);
    float p    = __expf(sp - mn);
    l  = l*corr + p;
    of = of*corr + p*vv;
    m = mn;
  }
  xo[qrow + lane] = f2bf(of / l);
}

extern "C" void kernel_launch(void* const* d_in, const int* in_sizes, int n_in,
                              void* d_out, int out_size, void* d_ws, size_t ws_size,
                              hipStream_t stream){
  (void)in_sizes; (void)n_in;
  // All float tensors are f32 on device (proven: f32 npz footprint; bf16 misread -> NaN).
  const float* Q  = (const float*)d_in[0];
  const float* K  = (const float*)d_in[1];
  const float* V  = (const float*)d_in[2];
  const int*  pos = (const int*)  d_in[3];
  const float* wq = (const float*)d_in[4];
  const float* wk = (const float*)d_in[5];
  const float* wv = (const float*)d_in[6];
  const float* wo = (const float*)d_in[7];

  const size_t SZ = (size_t)MR*DMn;          // 4,194,304 elements
  const size_t TB = SZ*2;                    // 8 MB per bf16 intermediate tensor
  // diagnostic guard: 0x42 pattern -> f32 ~48.6 -> absmax ~52 identifies ws shortage
  if (ws_size < 4*TB){
    hipMemsetAsync(d_out, 0x42, (size_t)out_size*4, stream);
    return;
  }
  char* w = (char*)d_ws;
  u16* xq = (u16*)(w);
  u16* xk = (u16*)(w + TB);
  u16* xv = (u16*)(w + 2*TB);
  u16* xo = (u16*)(w + 3*TB);

  dim3 gg(DMn/64, MR/64);                    // (16, 64)
  gemm_naive<float,u16><<<gg, 256, 0, stream>>>(Q, wq, xq);
  gemm_naive<float,u16><<<gg, 256, 0, stream>>>(K, wk, xk);
  gemm_naive<float,u16><<<gg, 256, 0, stream>>>(V, wv, xv);

  rope_kernel<<<(int)(SZ/2/256), 256, 0, stream>>>((u32*)xq, pos);
  rope_kernel<<<(int)(SZ/2/256), 256, 0, stream>>>((u32*)xk, pos);

  attn2_kernel<<<(BATCHn*NHn*SEQn)/4, 256, 0, stream>>>(xq, xk, xv, xo);

  // OUTPUT IS F32 — this was the round-0..3 bug (bf16 u16s packed into a float* buffer)
  gemm_naive<u16,float><<<gg, 256, 0, stream>>>(xo, wo, (float*)d_out);
}

// Round 6
// 825.486 us; speedup vs baseline: 6.5760x; 6.5760x over previous
//
#include <hip/hip_runtime.h>

typedef unsigned short u16;
typedef unsigned int u32;
using bf16x8 = __attribute__((ext_vector_type(8))) __bf16;
using f32x4  = __attribute__((ext_vector_type(4))) float;

#define SEQn   2048
#define DMn    1024
#define NHn    16
#define DKn    64
#define BATCHn 2
#define MR     (BATCHn*SEQn)   // 4096 rows

__device__ __forceinline__ u16 f2bf(float f){
  u32 u = __builtin_bit_cast(u32, f);
  u32 r = (u + 0x7FFFu + ((u >> 16) & 1u)) >> 16;   // RNE
  return (u16)r;
}
__device__ __forceinline__ float bf2f(u32 b){ return __builtin_bit_cast(float, b << 16); }

// ---------------- RoPE in place on bf16 tensor [m][h][d], inline sincos ----------------
__global__ __launch_bounds__(256) void rope_kernel(u32* __restrict__ x, const int* __restrict__ pos){
  int p = blockIdx.x*256 + threadIdx.x;       // exact grid: MR*DMn/2 pairs
  int s = (p >> 9) & (SEQn - 1);
  int k = p & 31;
  float inv = powf(10000.0f, -(float)k * (1.0f/32.0f));   // theta^(-2k/64)
  float a = (float)pos[s] * inv;
  float sn, cs;
  sincosf(a, &sn, &cs);
  u32 u = x[p];
  float xe = bf2f(u & 0xffffu);
  float xo = bf2f(u >> 16);
  float re = xe*cs - xo*sn;
  float ro = xe*sn + xo*cs;
  x[p] = (u32)f2bf(re) | ((u32)f2bf(ro) << 16);
}

// ---------------- simple VALU f32 GEMM: C[M][1024] = A[M][1024] * W[1024][1024]^T ----------------
template<typename AT, typename CT>
__global__ __launch_bounds__(256) void gemm_naive(const AT* __restrict__ A, const float* __restrict__ W,
                                                  CT* __restrict__ C){
  __shared__ float As[64][33];
  __shared__ float Ws[64][33];
  const int tid = threadIdx.x;
  const int m0 = blockIdx.y*64, n0 = blockIdx.x*64;
  const int tr = tid >> 4, tc = tid & 15;     // 16x16 thread grid, 4x4 each
  float acc[4][4] = {};
  const int sr = tid >> 2;                    // staging row 0..63
  const int sk = (tid & 3) * 8;               // staging k-offset {0,8,16,24}

  for (int kt = 0; kt < DMn; kt += 32){
    __syncthreads();
    if constexpr (sizeof(AT) == 2){
      const u16* ap = (const u16*)A + (size_t)(m0 + sr)*DMn + kt + sk;
#pragma unroll
      for (int e = 0; e < 8; e++) As[sr][sk + e] = bf2f(ap[e]);
    } else {
      const float* ap = (const float*)A + (size_t)(m0 + sr)*DMn + kt + sk;
#pragma unroll
      for (int e = 0; e < 8; e++) As[sr][sk + e] = ap[e];
    }
    {
      const float* wp = W + (size_t)(n0 + sr)*DMn + kt + sk;
#pragma unroll
      for (int e = 0; e < 8; e++) Ws[sr][sk + e] = wp[e];
    }
    __syncthreads();
#pragma unroll
    for (int kk = 0; kk < 32; kk++){
      float a[4], w[4];
#pragma unroll
      for (int x = 0; x < 4; x++){ a[x] = As[tr*4 + x][kk]; w[x] = Ws[tc*4 + x][kk]; }
#pragma unroll
      for (int x = 0; x < 4; x++)
#pragma unroll
        for (int y = 0; y < 4; y++) acc[x][y] = fmaf(a[x], w[y], acc[x][y]);
    }
  }
#pragma unroll
  for (int x = 0; x < 4; x++)
#pragma unroll
    for (int y = 0; y < 4; y++){
      if constexpr (sizeof(CT) == 2)
        C[(size_t)(m0 + tr*4 + x)*DMn + (n0 + tc*4 + y)] = f2bf(acc[x][y]);
      else
        C[(size_t)(m0 + tr*4 + x)*DMn + (n0 + tc*4 + y)] = acc[x][y];
    }
}

// ---------------- MFMA causal flash attention ----------------
// Block: 64 queries of one (b,h); 4 waves x 16 queries. 64-key tiles.
// Layouts (16x16x32 bf16 MFMA, m89/m91-verified):
//   A-frag: lane supplies A row (lane&15), k-offset (lane>>4)*8
//   B-frag: lane supplies B col (lane&15), k-offset (lane>>4)*8
//   C/D:    col = lane&15, row = (lane>>4)*4 + reg
// LDS tiles XOR-swizzled: 16B-chunk index ^= (row&7)  [G4 fix for 128B row stride]
__global__ __launch_bounds__(256) void attn_mfma(const u16* __restrict__ xq, const u16* __restrict__ xk,
                                                 const u16* __restrict__ xv, u16* __restrict__ xo){
  __shared__ u16 Kl[64*64];       // [k_local][d], swizzled
  __shared__ u16 Vt[64*64];       // [d][k_local], swizzled
  __shared__ u16 Pl[4][16*64];    // per-wave P [q_local][k_local], swizzled
  const int tid = threadIdx.x, lane = tid & 63, w = tid >> 6;
  const int bh = blockIdx.y, b = bh >> 4, h = bh & 15;
  const int q0 = blockIdx.x * 64, qw = q0 + w*16;
  const int l15 = lane & 15, lg = lane >> 4;

  // Q fragments (held for whole kernel): A row m=l15 -> query qw+l15
  const u16* qptr = xq + (size_t)(b*SEQn + qw + l15)*DMn + h*DKn + lg*8;
  const bf16x8 qf0 = *(const bf16x8*)(qptr);
  const bf16x8 qf1 = *(const bf16x8*)(qptr + 32);

  float mrow[4], lrow[4];
  f32x4 accO[4];
#pragma unroll
  for (int r = 0; r < 4; r++){ mrow[r] = -3e38f; lrow[r] = 0.f; }
#pragma unroll
  for (int df = 0; df < 4; df++) accO[df] = (f32x4){0.f,0.f,0.f,0.f};

  const int ntiles = blockIdx.x + 1;
  for (int t = 0; t < ntiles; t++){
    const int kt = t*64;
    __syncthreads();
    { // stage K tile: thread -> row tid>>2, two 16B chunks
      const int row = tid >> 2, c2 = (tid & 3)*2;
      const u16* src = xk + (size_t)(b*SEQn + kt + row)*DMn + h*DKn + c2*8;
      uint4 u0 = *(const uint4*)src;
      uint4 u1 = *(const uint4*)(src + 8);
      *(uint4*)&Kl[row*64 + (( c2    ^ (row&7))<<3)] = u0;
      *(uint4*)&Kl[row*64 + (((c2+1) ^ (row&7))<<3)] = u1;
    }
    { // stage V transposed: thread -> key tid&63, d-range (tid>>6)*16..+15
      const int k = tid & 63, dbase = (tid >> 6)*16;
      const u16* src = xv + (size_t)(b*SEQn + kt + k)*DMn + h*DKn + dbase;
      uint4 u0 = *(const uint4*)src;
      uint4 u1 = *(const uint4*)(src + 8);
      u16 tmp[16];
      *(uint4*)&tmp[0] = u0; *(uint4*)&tmp[8] = u1;
#pragma unroll
      for (int j = 0; j < 16; j++){
        const int d = dbase + j;
        Vt[d*64 + (((k>>3) ^ (d&7))<<3) + (k&7)] = tmp[j];
      }
    }
    __syncthreads();

    // S = Q K^T for 4 key fragments
    f32x4 sc[4];
#pragma unroll
    for (int f = 0; f < 4; f++){
      const int n = 16*f + l15;
      bf16x8 kb0 = *(const bf16x8*)&Kl[n*64 + (( lg    ^ (n&7))<<3)];
      bf16x8 kb1 = *(const bf16x8*)&Kl[n*64 + (((lg+4) ^ (n&7))<<3)];
      f32x4 z = (f32x4){0.f,0.f,0.f,0.f};
      z = __builtin_amdgcn_mfma_f32_16x16x32_bf16(qf0, kb0, z, 0, 0, 0);
      z = __builtin_amdgcn_mfma_f32_16x16x32_bf16(qf1, kb1, z, 0, 0, 0);
      sc[f] = z;
    }

    // scale + causal mask (only the diagonal tile needs it) + row max
    const bool needmask = (kt + 63 > qw);
    float mx[4];
#pragma unroll
    for (int r = 0; r < 4; r++){
      float v0 = sc[0][r]*0.125f, v1 = sc[1][r]*0.125f;
      float v2 = sc[2][r]*0.125f, v3 = sc[3][r]*0.125f;
      if (needmask){
        const int qg = qw + lg*4 + r;
        if (kt +      l15 > qg) v0 = -3e38f;
        if (kt + 16 + l15 > qg) v1 = -3e38f;
        if (kt + 32 + l15 > qg) v2 = -3e38f;
        if (kt + 48 + l15 > qg) v3 = -3e38f;
      }
      sc[0][r]=v0; sc[1][r]=v1; sc[2][r]=v2; sc[3][r]=v3;
      mx[r] = fmaxf(fmaxf(v0,v1), fmaxf(v2,v3));
    }
#pragma unroll
    for (int r = 0; r < 4; r++){
      float v = mx[r];
      v = fmaxf(v, __shfl_xor(v, 1));
      v = fmaxf(v, __shfl_xor(v, 2));
      v = fmaxf(v, __shfl_xor(v, 4));
      v = fmaxf(v, __shfl_xor(v, 8));
      mx[r] = v;
    }
    // P = exp(S-m), write to per-wave LDS; online rescale of l and accO
#pragma unroll
    for (int r = 0; r < 4; r++){
      const float mn = fmaxf(mrow[r], mx[r]);
      const float corr = __expf(mrow[r] - mn);
      mrow[r] = mn;
      const float p0 = __expf(sc[0][r]-mn), p1 = __expf(sc[1][r]-mn);
      const float p2 = __expf(sc[2][r]-mn), p3 = __expf(sc[3][r]-mn);
      const int q = lg*4 + r, qb = q*64, qx = q&7;
      const int k0 = l15, k1 = 16+l15, k2 = 32+l15, k3 = 48+l15;
      Pl[w][qb + (((k0>>3) ^ qx)<<3) + (k0&7)] = f2bf(p0);
      Pl[w][qb + (((k1>>3) ^ qx)<<3) + (k1&7)] = f2bf(p1);
      Pl[w][qb + (((k2>>3) ^ qx)<<3) + (k2&7)] = f2bf(p2);
      Pl[w][qb + (((k3>>3) ^ qx)<<3) + (k3&7)] = f2bf(p3);
      float s = ((p0+p1)+(p2+p3));
      s += __shfl_xor(s, 1);
      s += __shfl_xor(s, 2);
      s += __shfl_xor(s, 4);
      s += __shfl_xor(s, 8);
      lrow[r] = lrow[r]*corr + s;
      accO[0][r] *= corr; accO[1][r] *= corr; accO[2][r] *= corr; accO[3][r] *= corr;
    }
    // O += P V  (A = P from LDS, B = Vt)
#pragma unroll
    for (int ks = 0; ks < 2; ks++){
      bf16x8 pa = *(const bf16x8*)&Pl[w][ l15*64 + (((4*ks + lg) ^ (l15&7))<<3) ];
#pragma unroll
      for (int df = 0; df < 4; df++){
        const int d = 16*df + l15;
        bf16x8 vb = *(const bf16x8*)&Vt[ d*64 + (((4*ks + lg) ^ (d&7))<<3) ];
        accO[df] = __builtin_amdgcn_mfma_f32_16x16x32_bf16(pa, vb, accO[df], 0, 0, 0);
      }
    }
  }

  // epilogue: normalize and write xo rows (q = qw + lg*4 + r, d = 16*df + l15)
#pragma unroll
  for (int r = 0; r < 4; r++){
    const float inv = 1.0f / lrow[r];
    const int qg = qw + lg*4 + r;
    u16* dst = xo + (size_t)(b*SEQn + qg)*DMn + h*DKn;
#pragma unroll
    for (int df = 0; df < 4; df++)
      dst[16*df + l15] = f2bf(accO[df][r] * inv);
  }
}

extern "C" void kernel_launch(void* const* d_in, const int* in_sizes, int n_in,
                              void* d_out, int out_size, void* d_ws, size_t ws_size,
                              hipStream_t stream){
  (void)in_sizes; (void)n_in;
  const float* Q  = (const float*)d_in[0];
  const float* K  = (const float*)d_in[1];
  const float* V  = (const float*)d_in[2];
  const int*  pos = (const int*)  d_in[3];
  const float* wq = (const float*)d_in[4];
  const float* wk = (const float*)d_in[5];
  const float* wv = (const float*)d_in[6];
  const float* wo = (const float*)d_in[7];

  const size_t SZ = (size_t)MR*DMn;          // 4,194,304 elements
  const size_t TB = SZ*2;                    // 8 MB per bf16 intermediate tensor
  if (ws_size < 4*TB){
    hipMemsetAsync(d_out, 0x42, (size_t)out_size*4, stream);
    return;
  }
  char* w = (char*)d_ws;
  u16* xq = (u16*)(w);
  u16* xk = (u16*)(w + TB);
  u16* xv = (u16*)(w + 2*TB);
  u16* xo = (u16*)(w + 3*TB);

  dim3 gg(DMn/64, MR/64);                    // (16, 64)
  gemm_naive<float,u16><<<gg, 256, 0, stream>>>(Q, wq, xq);
  gemm_naive<float,u16><<<gg, 256, 0, stream>>>(K, wk, xk);
  gemm_naive<float,u16><<<gg, 256, 0, stream>>>(V, wv, xv);

  rope_kernel<<<(int)(SZ/2/256), 256, 0, stream>>>((u32*)xq, pos);
  rope_kernel<<<(int)(SZ/2/256), 256, 0, stream>>>((u32*)xk, pos);

  dim3 ag(SEQn/64, BATCHn*NHn);              // (32, 32)
  attn_mfma<<<ag, 256, 0, stream>>>(xq, xk, xv, xo);

  gemm_naive<u16,float><<<gg, 256, 0, stream>>>(xo, wo, (float*)d_out);
}

// Round 7
// 268.246 us; speedup vs baseline: 20.2367x; 3.0774x over previous
//
#include <hip/hip_runtime.h>

typedef unsigned short u16;
typedef unsigned int u32;
using bf16x8 = __attribute__((ext_vector_type(8))) __bf16;
using f32x4  = __attribute__((ext_vector_type(4))) float;

#define SEQn   2048
#define DMn    1024
#define NHn    16
#define DKn    64
#define BATCHn 2
#define MR     (BATCHn*SEQn)   // 4096 rows

__device__ __forceinline__ u16 f2bf(float f){
  u32 u = __builtin_bit_cast(u32, f);
  u32 r = (u + 0x7FFFu + ((u >> 16) & 1u)) >> 16;   // RNE
  return (u16)r;
}
__device__ __forceinline__ float bf2f(u32 b){ return __builtin_bit_cast(float, b << 16); }

// ---------------- RoPE in place on bf16 tensor [m][h][d], inline sincos ----------------
__global__ __launch_bounds__(256) void rope_kernel(u32* __restrict__ x, const int* __restrict__ pos){
  int p = blockIdx.x*256 + threadIdx.x;       // exact grid: MR*DMn/2 pairs
  int s = (p >> 9) & (SEQn - 1);
  int k = p & 31;
  float inv = powf(10000.0f, -(float)k * (1.0f/32.0f));   // theta^(-2k/64)
  float a = (float)pos[s] * inv;
  float sn, cs;
  sincosf(a, &sn, &cs);
  u32 u = x[p];
  float xe = bf2f(u & 0xffffu);
  float xo = bf2f(u >> 16);
  float re = xe*cs - xo*sn;
  float ro = xe*sn + xo*cs;
  x[p] = (u32)f2bf(re) | ((u32)f2bf(ro) << 16);
}

// ---------------- MFMA GEMM body: C[M][1024] = A[M][1024] * W[1024][1024]^T ----------------
// 128x128 tile, BK=64, 256 threads (4 waves 2x2, 64x64 per wave), 16x16x32 bf16 MFMA.
// LDS [128][64] u16, 16B-chunk XOR swizzle: phys_chunk = chunk ^ (row&7)  -> 2-way (free).
// Fragment mappings HW-validated by round-6 attn_mfma PASS.
template<typename AT, typename CT>
__device__ __forceinline__ void gemm_body(const AT* __restrict__ A, const float* __restrict__ W,
                                          CT* __restrict__ C, int bx, int by){
  __shared__ u16 As[128*64];
  __shared__ u16 Bs[128*64];
  const int tid = threadIdx.x, lane = tid & 63, w = tid >> 6;
  const int m0 = by*128, n0 = bx*128;
  const int wr = (w >> 1)*64, wc = (w & 1)*64;
  const int l15 = lane & 15, lg = lane >> 4;
  f32x4 acc[4][4];
#pragma unroll
  for (int i = 0; i < 4; i++)
#pragma unroll
    for (int j = 0; j < 4; j++) acc[i][j] = (f32x4){0.f,0.f,0.f,0.f};

  for (int kt = 0; kt < DMn; kt += 64){
    // ---- load tiles to regs (coalesced) ----
    float4 wv[8];
#pragma unroll
    for (int it = 0; it < 8; it++){
      const int f = it*256 + tid, row = f >> 4, c4 = f & 15;
      wv[it] = *(const float4*)(W + (size_t)(n0 + row)*DMn + kt + c4*4);
    }
    if constexpr (sizeof(AT) == 4){
      float4 av[8];
#pragma unroll
      for (int it = 0; it < 8; it++){
        const int f = it*256 + tid, row = f >> 4, c4 = f & 15;
        av[it] = *(const float4*)((const float*)A + (size_t)(m0 + row)*DMn + kt + c4*4);
      }
      __syncthreads();
#pragma unroll
      for (int it = 0; it < 8; it++){
        const int f = it*256 + tid, row = f >> 4, c4 = f & 15;
        ushort4 o = { f2bf(av[it].x), f2bf(av[it].y), f2bf(av[it].z), f2bf(av[it].w) };
        *(ushort4*)&As[row*64 + (((c4>>1) ^ (row&7))<<3) + ((c4&1)<<2)] = o;
      }
    } else {
      uint4 av4[4];
#pragma unroll
      for (int it = 0; it < 4; it++){
        const int f = it*256 + tid, row = f >> 3, ch = f & 7;
        av4[it] = *(const uint4*)((const u16*)A + (size_t)(m0 + row)*DMn + kt + ch*8);
      }
      __syncthreads();
#pragma unroll
      for (int it = 0; it < 4; it++){
        const int f = it*256 + tid, row = f >> 3, ch = f & 7;
        *(uint4*)&As[row*64 + ((ch ^ (row&7))<<3)] = av4[it];
      }
    }
#pragma unroll
    for (int it = 0; it < 8; it++){
      const int f = it*256 + tid, row = f >> 4, c4 = f & 15;
      ushort4 o = { f2bf(wv[it].x), f2bf(wv[it].y), f2bf(wv[it].z), f2bf(wv[it].w) };
      *(ushort4*)&Bs[row*64 + (((c4>>1) ^ (row&7))<<3) + ((c4&1)<<2)] = o;
    }
    __syncthreads();

    // ---- compute: 2 k-substeps of 32 ----
#pragma unroll
    for (int kk = 0; kk < 2; kk++){
      bf16x8 af[4], bfr[4];
      const int ch = kk*4 + lg;
#pragma unroll
      for (int i = 0; i < 4; i++){
        const int row = wr + i*16 + l15;
        af[i] = *(const bf16x8*)&As[row*64 + ((ch ^ (row&7))<<3)];
      }
#pragma unroll
      for (int j = 0; j < 4; j++){
        const int col = wc + j*16 + l15;
        bfr[j] = *(const bf16x8*)&Bs[col*64 + ((ch ^ (col&7))<<3)];
      }
#pragma unroll
      for (int i = 0; i < 4; i++)
#pragma unroll
        for (int j = 0; j < 4; j++)
          acc[i][j] = __builtin_amdgcn_mfma_f32_16x16x32_bf16(af[i], bfr[j], acc[i][j], 0, 0, 0);
    }
    __syncthreads();
  }

  // ---- epilogue: C/D layout col=lane&15, row=(lane>>4)*4+reg ----
#pragma unroll
  for (int i = 0; i < 4; i++)
#pragma unroll
    for (int j = 0; j < 4; j++)
#pragma unroll
      for (int r = 0; r < 4; r++){
        const int row = m0 + wr + i*16 + lg*4 + r;
        const int col = n0 + wc + j*16 + l15;
        if constexpr (sizeof(CT) == 2) C[(size_t)row*DMn + col] = f2bf(acc[i][j][r]);
        else                           C[(size_t)row*DMn + col] = acc[i][j][r];
      }
}

// fused Q/K/V projections: blockIdx.z selects the (A, W, C) triple
__global__ __launch_bounds__(256) void gemm_qkv(const float* A0, const float* A1, const float* A2,
                                                const float* W0, const float* W1, const float* W2,
                                                u16* C0, u16* C1, u16* C2){
  const int z = blockIdx.z;
  const float* A = (z == 0) ? A0 : (z == 1) ? A1 : A2;
  const float* W = (z == 0) ? W0 : (z == 1) ? W1 : W2;
  u16*         C = (z == 0) ? C0 : (z == 1) ? C1 : C2;
  gemm_body<float, u16>(A, W, C, blockIdx.x, blockIdx.y);
}

__global__ __launch_bounds__(256) void gemm_out(const u16* A, const float* W, float* C){
  gemm_body<u16, float>(A, W, C, blockIdx.x, blockIdx.y);
}

// ---------------- MFMA causal flash attention (round-6, validated) ----------------
__global__ __launch_bounds__(256) void attn_mfma(const u16* __restrict__ xq, const u16* __restrict__ xk,
                                                 const u16* __restrict__ xv, u16* __restrict__ xo){
  __shared__ u16 Kl[64*64];       // [k_local][d], swizzled
  __shared__ u16 Vt[64*64];       // [d][k_local], swizzled
  __shared__ u16 Pl[4][16*64];    // per-wave P [q_local][k_local], swizzled
  const int tid = threadIdx.x, lane = tid & 63, w = tid >> 6;
  const int bh = blockIdx.y, b = bh >> 4, h = bh & 15;
  const int q0 = blockIdx.x * 64, qw = q0 + w*16;
  const int l15 = lane & 15, lg = lane >> 4;

  const u16* qptr = xq + (size_t)(b*SEQn + qw + l15)*DMn + h*DKn + lg*8;
  const bf16x8 qf0 = *(const bf16x8*)(qptr);
  const bf16x8 qf1 = *(const bf16x8*)(qptr + 32);

  float mrow[4], lrow[4];
  f32x4 accO[4];
#pragma unroll
  for (int r = 0; r < 4; r++){ mrow[r] = -3e38f; lrow[r] = 0.f; }
#pragma unroll
  for (int df = 0; df < 4; df++) accO[df] = (f32x4){0.f,0.f,0.f,0.f};

  const int ntiles = blockIdx.x + 1;
  for (int t = 0; t < ntiles; t++){
    const int kt = t*64;
    __syncthreads();
    {
      const int row = tid >> 2, c2 = (tid & 3)*2;
      const u16* src = xk + (size_t)(b*SEQn + kt + row)*DMn + h*DKn + c2*8;
      uint4 u0 = *(const uint4*)src;
      uint4 u1 = *(const uint4*)(src + 8);
      *(uint4*)&Kl[row*64 + (( c2    ^ (row&7))<<3)] = u0;
      *(uint4*)&Kl[row*64 + (((c2+1) ^ (row&7))<<3)] = u1;
    }
    {
      const int k = tid & 63, dbase = (tid >> 6)*16;
      const u16* src = xv + (size_t)(b*SEQn + kt + k)*DMn + h*DKn + dbase;
      uint4 u0 = *(const uint4*)src;
      uint4 u1 = *(const uint4*)(src + 8);
      u16 tmp[16];
      *(uint4*)&tmp[0] = u0; *(uint4*)&tmp[8] = u1;
#pragma unroll
      for (int j = 0; j < 16; j++){
        const int d = dbase + j;
        Vt[d*64 + (((k>>3) ^ (d&7))<<3) + (k&7)] = tmp[j];
      }
    }
    __syncthreads();

    f32x4 sc[4];
#pragma unroll
    for (int f = 0; f < 4; f++){
      const int n = 16*f + l15;
      bf16x8 kb0 = *(const bf16x8*)&Kl[n*64 + (( lg    ^ (n&7))<<3)];
      bf16x8 kb1 = *(const bf16x8*)&Kl[n*64 + (((lg+4) ^ (n&7))<<3)];
      f32x4 z = (f32x4){0.f,0.f,0.f,0.f};
      z = __builtin_amdgcn_mfma_f32_16x16x32_bf16(qf0, kb0, z, 0, 0, 0);
      z = __builtin_amdgcn_mfma_f32_16x16x32_bf16(qf1, kb1, z, 0, 0, 0);
      sc[f] = z;
    }

    const bool needmask = (kt + 63 > qw);
    float mx[4];
#pragma unroll
    for (int r = 0; r < 4; r++){
      float v0 = sc[0][r]*0.125f, v1 = sc[1][r]*0.125f;
      float v2 = sc[2][r]*0.125f, v3 = sc[3][r]*0.125f;
      if (needmask){
        const int qg = qw + lg*4 + r;
        if (kt +      l15 > qg) v0 = -3e38f;
        if (kt + 16 + l15 > qg) v1 = -3e38f;
        if (kt + 32 + l15 > qg) v2 = -3e38f;
        if (kt + 48 + l15 > qg) v3 = -3e38f;
      }
      sc[0][r]=v0; sc[1][r]=v1; sc[2][r]=v2; sc[3][r]=v3;
      mx[r] = fmaxf(fmaxf(v0,v1), fmaxf(v2,v3));
    }
#pragma unroll
    for (int r = 0; r < 4; r++){
      float v = mx[r];
      v = fmaxf(v, __shfl_xor(v, 1));
      v = fmaxf(v, __shfl_xor(v, 2));
      v = fmaxf(v, __shfl_xor(v, 4));
      v = fmaxf(v, __shfl_xor(v, 8));
      mx[r] = v;
    }
#pragma unroll
    for (int r = 0; r < 4; r++){
      const float mn = fmaxf(mrow[r], mx[r]);
      const float corr = __expf(mrow[r] - mn);
      mrow[r] = mn;
      const float p0 = __expf(sc[0][r]-mn), p1 = __expf(sc[1][r]-mn);
      const float p2 = __expf(sc[2][r]-mn), p3 = __expf(sc[3][r]-mn);
      const int q = lg*4 + r, qb = q*64, qx = q&7;
      const int k0 = l15, k1 = 16+l15, k2 = 32+l15, k3 = 48+l15;
      Pl[w][qb + (((k0>>3) ^ qx)<<3) + (k0&7)] = f2bf(p0);
      Pl[w][qb + (((k1>>3) ^ qx)<<3) + (k1&7)] = f2bf(p1);
      Pl[w][qb + (((k2>>3) ^ qx)<<3) + (k2&7)] = f2bf(p2);
      Pl[w][qb + (((k3>>3) ^ qx)<<3) + (k3&7)] = f2bf(p3);
      float s = ((p0+p1)+(p2+p3));
      s += __shfl_xor(s, 1);
      s += __shfl_xor(s, 2);
      s += __shfl_xor(s, 4);
      s += __shfl_xor(s, 8);
      lrow[r] = lrow[r]*corr + s;
      accO[0][r] *= corr; accO[1][r] *= corr; accO[2][r] *= corr; accO[3][r] *= corr;
    }
#pragma unroll
    for (int ks = 0; ks < 2; ks++){
      bf16x8 pa = *(const bf16x8*)&Pl[w][ l15*64 + (((4*ks + lg) ^ (l15&7))<<3) ];
#pragma unroll
      for (int df = 0; df < 4; df++){
        const int d = 16*df + l15;
        bf16x8 vb = *(const bf16x8*)&Vt[ d*64 + (((4*ks + lg) ^ (d&7))<<3) ];
        accO[df] = __builtin_amdgcn_mfma_f32_16x16x32_bf16(pa, vb, accO[df], 0, 0, 0);
      }
    }
  }

#pragma unroll
  for (int r = 0; r < 4; r++){
    const float inv = 1.0f / lrow[r];
    const int qg = qw + lg*4 + r;
    u16* dst = xo + (size_t)(b*SEQn + qg)*DMn + h*DKn;
#pragma unroll
    for (int df = 0; df < 4; df++)
      dst[16*df + l15] = f2bf(accO[df][r] * inv);
  }
}

extern "C" void kernel_launch(void* const* d_in, const int* in_sizes, int n_in,
                              void* d_out, int out_size, void* d_ws, size_t ws_size,
                              hipStream_t stream){
  (void)in_sizes; (void)n_in;
  const float* Q  = (const float*)d_in[0];
  const float* K  = (const float*)d_in[1];
  const float* V  = (const float*)d_in[2];
  const int*  pos = (const int*)  d_in[3];
  const float* wq = (const float*)d_in[4];
  const float* wk = (const float*)d_in[5];
  const float* wv = (const float*)d_in[6];
  const float* wo = (const float*)d_in[7];

  const size_t SZ = (size_t)MR*DMn;          // 4,194,304 elements
  const size_t TB = SZ*2;                    // 8 MB per bf16 intermediate tensor
  if (ws_size < 4*TB){
    hipMemsetAsync(d_out, 0x42, (size_t)out_size*4, stream);
    return;
  }
  char* w = (char*)d_ws;
  u16* xq = (u16*)(w);
  u16* xk = (u16*)(w + TB);
  u16* xv = (u16*)(w + 2*TB);
  u16* xo = (u16*)(w + 3*TB);

  dim3 gg(DMn/128, MR/128, 3);               // (8, 32, 3): Q,K,V projections in one dispatch
  gemm_qkv<<<gg, 256, 0, stream>>>(Q, K, V, wq, wk, wv, xq, xk, xv);

  rope_kernel<<<(int)(SZ/2/256), 256, 0, stream>>>((u32*)xq, pos);
  rope_kernel<<<(int)(SZ/2/256), 256, 0, stream>>>((u32*)xk, pos);

  dim3 ag(SEQn/64, BATCHn*NHn);              // (32, 32)
  attn_mfma<<<ag, 256, 0, stream>>>(xq, xk, xv, xo);

  dim3 go(DMn/128, MR/128);                  // (8, 32)
  gemm_out<<<go, 256, 0, stream>>>(xo, wo, (float*)d_out);
}

// Round 8
// 218.732 us; speedup vs baseline: 24.8176x; 1.2264x over previous
//
#include <hip/hip_runtime.h>

typedef unsigned short u16;
typedef unsigned int u32;
using bf16x8 = __attribute__((ext_vector_type(8))) __bf16;
using f32x4  = __attribute__((ext_vector_type(4))) float;

#define SEQn   2048
#define DMn    1024
#define NHn    16
#define DKn    64
#define BATCHn 2
#define MR     (BATCHn*SEQn)   // 4096 rows

__device__ __forceinline__ u16 f2bf(float f){
  u32 u = __builtin_bit_cast(u32, f);
  u32 r = (u + 0x7FFFu + ((u >> 16) & 1u)) >> 16;   // RNE
  return (u16)r;
}
__device__ __forceinline__ float bf2f(u32 b){ return __builtin_bit_cast(float, b << 16); }

// ---------------- RoPE in place on bf16 tensor [m][h][d], inline sincos ----------------
__global__ __launch_bounds__(256) void rope_kernel(u32* __restrict__ x, const int* __restrict__ pos){
  int p = blockIdx.x*256 + threadIdx.x;       // exact grid: MR*DMn/2 pairs
  int s = (p >> 9) & (SEQn - 1);
  int k = p & 31;
  float inv = powf(10000.0f, -(float)k * (1.0f/32.0f));   // theta^(-2k/64)
  float a = (float)pos[s] * inv;
  float sn, cs;
  sincosf(a, &sn, &cs);
  u32 u = x[p];
  float xe = bf2f(u & 0xffffu);
  float xo = bf2f(u >> 16);
  float re = xe*cs - xo*sn;
  float ro = xe*sn + xo*cs;
  x[p] = (u32)f2bf(re) | ((u32)f2bf(ro) << 16);
}

// ---------------- MFMA GEMM body (round-7, validated): C = A * W^T ----------------
template<typename AT, typename CT>
__device__ __forceinline__ void gemm_body(const AT* __restrict__ A, const float* __restrict__ W,
                                          CT* __restrict__ C, int bx, int by){
  __shared__ u16 As[128*64];
  __shared__ u16 Bs[128*64];
  const int tid = threadIdx.x, lane = tid & 63, w = tid >> 6;
  const int m0 = by*128, n0 = bx*128;
  const int wr = (w >> 1)*64, wc = (w & 1)*64;
  const int l15 = lane & 15, lg = lane >> 4;
  f32x4 acc[4][4];
#pragma unroll
  for (int i = 0; i < 4; i++)
#pragma unroll
    for (int j = 0; j < 4; j++) acc[i][j] = (f32x4){0.f,0.f,0.f,0.f};

  for (int kt = 0; kt < DMn; kt += 64){
    float4 wv[8];
#pragma unroll
    for (int it = 0; it < 8; it++){
      const int f = it*256 + tid, row = f >> 4, c4 = f & 15;
      wv[it] = *(const float4*)(W + (size_t)(n0 + row)*DMn + kt + c4*4);
    }
    if constexpr (sizeof(AT) == 4){
      float4 av[8];
#pragma unroll
      for (int it = 0; it < 8; it++){
        const int f = it*256 + tid, row = f >> 4, c4 = f & 15;
        av[it] = *(const float4*)((const float*)A + (size_t)(m0 + row)*DMn + kt + c4*4);
      }
      __syncthreads();
#pragma unroll
      for (int it = 0; it < 8; it++){
        const int f = it*256 + tid, row = f >> 4, c4 = f & 15;
        ushort4 o = { f2bf(av[it].x), f2bf(av[it].y), f2bf(av[it].z), f2bf(av[it].w) };
        *(ushort4*)&As[row*64 + (((c4>>1) ^ (row&7))<<3) + ((c4&1)<<2)] = o;
      }
    } else {
      uint4 av4[4];
#pragma unroll
      for (int it = 0; it < 4; it++){
        const int f = it*256 + tid, row = f >> 3, ch = f & 7;
        av4[it] = *(const uint4*)((const u16*)A + (size_t)(m0 + row)*DMn + kt + ch*8);
      }
      __syncthreads();
#pragma unroll
      for (int it = 0; it < 4; it++){
        const int f = it*256 + tid, row = f >> 3, ch = f & 7;
        *(uint4*)&As[row*64 + ((ch ^ (row&7))<<3)] = av4[it];
      }
    }
#pragma unroll
    for (int it = 0; it < 8; it++){
      const int f = it*256 + tid, row = f >> 4, c4 = f & 15;
      ushort4 o = { f2bf(wv[it].x), f2bf(wv[it].y), f2bf(wv[it].z), f2bf(wv[it].w) };
      *(ushort4*)&Bs[row*64 + (((c4>>1) ^ (row&7))<<3) + ((c4&1)<<2)] = o;
    }
    __syncthreads();

#pragma unroll
    for (int kk = 0; kk < 2; kk++){
      bf16x8 af[4], bfr[4];
      const int ch = kk*4 + lg;
#pragma unroll
      for (int i = 0; i < 4; i++){
        const int row = wr + i*16 + l15;
        af[i] = *(const bf16x8*)&As[row*64 + ((ch ^ (row&7))<<3)];
      }
#pragma unroll
      for (int j = 0; j < 4; j++){
        const int col = wc + j*16 + l15;
        bfr[j] = *(const bf16x8*)&Bs[col*64 + ((ch ^ (col&7))<<3)];
      }
#pragma unroll
      for (int i = 0; i < 4; i++)
#pragma unroll
        for (int j = 0; j < 4; j++)
          acc[i][j] = __builtin_amdgcn_mfma_f32_16x16x32_bf16(af[i], bfr[j], acc[i][j], 0, 0, 0);
    }
    __syncthreads();
  }

#pragma unroll
  for (int i = 0; i < 4; i++)
#pragma unroll
    for (int j = 0; j < 4; j++)
#pragma unroll
      for (int r = 0; r < 4; r++){
        const int row = m0 + wr + i*16 + lg*4 + r;
        const int col = n0 + wc + j*16 + l15;
        if constexpr (sizeof(CT) == 2) C[(size_t)row*DMn + col] = f2bf(acc[i][j][r]);
        else                           C[(size_t)row*DMn + col] = acc[i][j][r];
      }
}

__global__ __launch_bounds__(256) void gemm_qkv(const float* A0, const float* A1, const float* A2,
                                                const float* W0, const float* W1, const float* W2,
                                                u16* C0, u16* C1, u16* C2){
  const int z = blockIdx.z;
  const float* A = (z == 0) ? A0 : (z == 1) ? A1 : A2;
  const float* W = (z == 0) ? W0 : (z == 1) ? W1 : W2;
  u16*         C = (z == 0) ? C0 : (z == 1) ? C1 : C2;
  gemm_body<float, u16>(A, W, C, blockIdx.x, blockIdx.y);
}

__global__ __launch_bounds__(256) void gemm_out(const u16* A, const float* W, float* C){
  gemm_body<u16, float>(A, W, C, blockIdx.x, blockIdx.y);
}

// ---------------- MFMA causal flash attention, round-8 ----------------
// 512 blocks: block bx handles q-tiles bx AND 31-bx of one (b,h) -> exactly 33 K-tiles
// each (perfect causal balance). Double-buffered K/V staging, ONE barrier per tile
// (parity argument: iter-t writes touch the buffer last read at t-1, fenced by the
// end-of-(t-1) barrier). setprio(1) around MFMA clusters (T5).
struct StageRegs { uint4 k0, k1, v0, v1; };

__device__ __forceinline__ StageRegs stage_load(const u16* __restrict__ xk, const u16* __restrict__ xv,
                                                size_t bhbase, int kt, int tid){
  StageRegs r;
  const int row = tid >> 2, c2 = (tid & 3)*2;
  const u16* ks = xk + bhbase + (size_t)(kt + row)*DMn + c2*8;
  r.k0 = *(const uint4*)ks;
  r.k1 = *(const uint4*)(ks + 8);
  const int k = tid & 63, dbase = (tid >> 6)*16;
  const u16* vs = xv + bhbase + (size_t)(kt + k)*DMn + dbase;
  r.v0 = *(const uint4*)vs;
  r.v1 = *(const uint4*)(vs + 8);
  return r;
}

__device__ __forceinline__ void stage_write(u16* __restrict__ Kl, u16* __restrict__ Vt,
                                            const StageRegs& r, int tid){
  const int row = tid >> 2, c2 = (tid & 3)*2;
  *(uint4*)&Kl[row*64 + (( c2    ^ (row&7))<<3)] = r.k0;
  *(uint4*)&Kl[row*64 + (((c2+1) ^ (row&7))<<3)] = r.k1;
  const int k = tid & 63, dbase = (tid >> 6)*16;
  u16 tmp[16];
  *(uint4*)&tmp[0] = r.v0; *(uint4*)&tmp[8] = r.v1;
#pragma unroll
  for (int j = 0; j < 16; j++){
    const int d = dbase + j;
    Vt[d*64 + (((k>>3) ^ (d&7))<<3) + (k&7)] = tmp[j];
  }
}

__device__ __forceinline__ void attn_phase(const u16* __restrict__ xq, const u16* __restrict__ xk,
                                           const u16* __restrict__ xv, u16* __restrict__ xo,
                                           u16* __restrict__ Kl0, u16* __restrict__ Kl1,
                                           u16* __restrict__ Vt0, u16* __restrict__ Vt1,
                                           u16* __restrict__ Plw, size_t bhbase, int qt, int tid){
  const int lane = tid & 63, w = tid >> 6;
  const int l15 = lane & 15, lg = lane >> 4;
  const int qw = qt*64 + w*16;

  const u16* qptr = xq + bhbase + (size_t)(qw + l15)*DMn + lg*8;
  const bf16x8 qf0 = *(const bf16x8*)(qptr);
  const bf16x8 qf1 = *(const bf16x8*)(qptr + 32);

  float mrow[4], lrow[4];
  f32x4 accO[4];
#pragma unroll
  for (int r = 0; r < 4; r++){ mrow[r] = -3e38f; lrow[r] = 0.f; }
#pragma unroll
  for (int df = 0; df < 4; df++) accO[df] = (f32x4){0.f,0.f,0.f,0.f};

  StageRegs sr = stage_load(xk, xv, bhbase, 0, tid);
  stage_write(Kl0, Vt0, sr, tid);
  __syncthreads();

  for (int t = 0; t <= qt; t++){
    const int kt = t*64;
    u16* Kc = (t & 1) ? Kl1 : Kl0;
    u16* Vc = (t & 1) ? Vt1 : Vt0;
    if (t < qt) sr = stage_load(xk, xv, bhbase, kt + 64, tid);   // overlap HBM with compute

    // ---- S = Q K^T ----
    f32x4 sc[4];
    __builtin_amdgcn_s_setprio(1);
#pragma unroll
    for (int f = 0; f < 4; f++){
      const int n = 16*f + l15;
      bf16x8 kb0 = *(const bf16x8*)&Kc[n*64 + (( lg    ^ (n&7))<<3)];
      bf16x8 kb1 = *(const bf16x8*)&Kc[n*64 + (((lg+4) ^ (n&7))<<3)];
      f32x4 z = (f32x4){0.f,0.f,0.f,0.f};
      z = __builtin_amdgcn_mfma_f32_16x16x32_bf16(qf0, kb0, z, 0, 0, 0);
      z = __builtin_amdgcn_mfma_f32_16x16x32_bf16(qf1, kb1, z, 0, 0, 0);
      sc[f] = z;
    }
    __builtin_amdgcn_s_setprio(0);

    // ---- scale + mask (diagonal tile only) + row max ----
    const bool needmask = (kt + 63 > qw);
    float mx[4];
#pragma unroll
    for (int r = 0; r < 4; r++){
      float v0 = sc[0][r]*0.125f, v1 = sc[1][r]*0.125f;
      float v2 = sc[2][r]*0.125f, v3 = sc[3][r]*0.125f;
      if (needmask){
        const int qg = qw + lg*4 + r;
        if (kt +      l15 > qg) v0 = -3e38f;
        if (kt + 16 + l15 > qg) v1 = -3e38f;
        if (kt + 32 + l15 > qg) v2 = -3e38f;
        if (kt + 48 + l15 > qg) v3 = -3e38f;
      }
      sc[0][r]=v0; sc[1][r]=v1; sc[2][r]=v2; sc[3][r]=v3;
      mx[r] = fmaxf(fmaxf(v0,v1), fmaxf(v2,v3));
    }
#pragma unroll
    for (int r = 0; r < 4; r++){
      float v = mx[r];
      v = fmaxf(v, __shfl_xor(v, 1));
      v = fmaxf(v, __shfl_xor(v, 2));
      v = fmaxf(v, __shfl_xor(v, 4));
      v = fmaxf(v, __shfl_xor(v, 8));
      mx[r] = v;
    }
    // ---- P = exp(S-m) -> per-wave LDS; online rescale ----
#pragma unroll
    for (int r = 0; r < 4; r++){
      const float mn = fmaxf(mrow[r], mx[r]);
      const float corr = __expf(mrow[r] - mn);
      mrow[r] = mn;
      const float p0 = __expf(sc[0][r]-mn), p1 = __expf(sc[1][r]-mn);
      const float p2 = __expf(sc[2][r]-mn), p3 = __expf(sc[3][r]-mn);
      const int q = lg*4 + r, qb = q*64, qx = q&7;
      const int k0 = l15, k1 = 16+l15, k2 = 32+l15, k3 = 48+l15;
      Plw[qb + (((k0>>3) ^ qx)<<3) + (k0&7)] = f2bf(p0);
      Plw[qb + (((k1>>3) ^ qx)<<3) + (k1&7)] = f2bf(p1);
      Plw[qb + (((k2>>3) ^ qx)<<3) + (k2&7)] = f2bf(p2);
      Plw[qb + (((k3>>3) ^ qx)<<3) + (k3&7)] = f2bf(p3);
      float s = ((p0+p1)+(p2+p3));
      s += __shfl_xor(s, 1);
      s += __shfl_xor(s, 2);
      s += __shfl_xor(s, 4);
      s += __shfl_xor(s, 8);
      lrow[r] = lrow[r]*corr + s;
      accO[0][r] *= corr; accO[1][r] *= corr; accO[2][r] *= corr; accO[3][r] *= corr;
    }
    // ---- O += P V ----
    __builtin_amdgcn_s_setprio(1);
#pragma unroll
    for (int ks = 0; ks < 2; ks++){
      bf16x8 pa = *(const bf16x8*)&Plw[ l15*64 + (((4*ks + lg) ^ (l15&7))<<3) ];
#pragma unroll
      for (int df = 0; df < 4; df++){
        const int d = 16*df + l15;
        bf16x8 vb = *(const bf16x8*)&Vc[ d*64 + (((4*ks + lg) ^ (d&7))<<3) ];
        accO[df] = __builtin_amdgcn_mfma_f32_16x16x32_bf16(pa, vb, accO[df], 0, 0, 0);
      }
    }
    __builtin_amdgcn_s_setprio(0);

    if (t < qt) stage_write((t & 1) ? Kl0 : Kl1, (t & 1) ? Vt0 : Vt1, sr, tid);
    __syncthreads();
  }

  // ---- epilogue ----
#pragma unroll
  for (int r = 0; r < 4; r++){
    const float inv = 1.0f / lrow[r];
    const int qg = qw + lg*4 + r;
    u16* dst = xo + bhbase + (size_t)qg*DMn;
#pragma unroll
    for (int df = 0; df < 4; df++)
      dst[16*df + l15] = f2bf(accO[df][r] * inv);
  }
}

__global__ __launch_bounds__(256) void attn_mfma(const u16* __restrict__ xq, const u16* __restrict__ xk,
                                                 const u16* __restrict__ xv, u16* __restrict__ xo){
  __shared__ u16 Kl[2][64*64];
  __shared__ u16 Vt[2][64*64];
  __shared__ u16 Pl[4][16*64];
  const int tid = threadIdx.x;
  const int bh = blockIdx.y, b = bh >> 4, h = bh & 15;
  const size_t bhbase = (size_t)b*SEQn*DMn + (size_t)h*DKn;
  const int bx = blockIdx.x;
  u16* Plw = &Pl[tid >> 6][0];

  attn_phase(xq, xk, xv, xo, &Kl[0][0], &Kl[1][0], &Vt[0][0], &Vt[1][0], Plw, bhbase, bx,      tid);
  attn_phase(xq, xk, xv, xo, &Kl[0][0], &Kl[1][0], &Vt[0][0], &Vt[1][0], Plw, bhbase, 31 - bx, tid);
}

extern "C" void kernel_launch(void* const* d_in, const int* in_sizes, int n_in,
                              void* d_out, int out_size, void* d_ws, size_t ws_size,
                              hipStream_t stream){
  (void)in_sizes; (void)n_in;
  const float* Q  = (const float*)d_in[0];
  const float* K  = (const float*)d_in[1];
  const float* V  = (const float*)d_in[2];
  const int*  pos = (const int*)  d_in[3];
  const float* wq = (const float*)d_in[4];
  const float* wk = (const float*)d_in[5];
  const float* wv = (const float*)d_in[6];
  const float* wo = (const float*)d_in[7];

  const size_t SZ = (size_t)MR*DMn;          // 4,194,304 elements
  const size_t TB = SZ*2;                    // 8 MB per bf16 intermediate tensor
  if (ws_size < 4*TB){
    hipMemsetAsync(d_out, 0x42, (size_t)out_size*4, stream);
    return;
  }
  char* w = (char*)d_ws;
  u16* xq = (u16*)(w);
  u16* xk = (u16*)(w + TB);
  u16* xv = (u16*)(w + 2*TB);
  u16* xo = (u16*)(w + 3*TB);

  dim3 gg(DMn/128, MR/128, 3);               // (8, 32, 3): Q,K,V projections in one dispatch
  gemm_qkv<<<gg, 256, 0, stream>>>(Q, K, V, wq, wk, wv, xq, xk, xv);

  rope_kernel<<<(int)(SZ/2/256), 256, 0, stream>>>((u32*)xq, pos);
  rope_kernel<<<(int)(SZ/2/256), 256, 0, stream>>>((u32*)xk, pos);

  dim3 ag(16, BATCHn*NHn);                   // 512 balanced blocks (paired causal q-tiles)
  attn_mfma<<<ag, 256, 0, stream>>>(xq, xk, xv, xo);

  dim3 go(DMn/128, MR/128);                  // (8, 32)
  gemm_out<<<go, 256, 0, stream>>>(xo, wo, (float*)d_out);
}

// Round 9
// 176.574 us; speedup vs baseline: 30.7431x; 1.2388x over previous
//
#include <hip/hip_runtime.h>

typedef unsigned short u16;
typedef unsigned int u32;
using bf16x8 = __attribute__((ext_vector_type(8))) __bf16;
using f32x4  = __attribute__((ext_vector_type(4))) float;

#define SEQn   2048
#define DMn    1024
#define NHn    16
#define DKn    64
#define BATCHn 2
#define MR     (BATCHn*SEQn)   // 4096 rows

__device__ __forceinline__ u16 f2bf(float f){
  u32 u = __builtin_bit_cast(u32, f);
  u32 r = (u + 0x7FFFu + ((u >> 16) & 1u)) >> 16;   // RNE
  return (u16)r;
}
__device__ __forceinline__ float bf2f(u32 b){ return __builtin_bit_cast(float, b << 16); }

// async global->LDS, 16B per lane (linear dest = wave base + lane*16)
__device__ __forceinline__ void gload16(const void* g, void* l){
  __builtin_amdgcn_global_load_lds((const __attribute__((address_space(1))) unsigned int*)g,
                                   (__attribute__((address_space(3))) unsigned int*)l, 16, 0, 0);
}

// ---------------- f32 -> bf16 converts (vectorized) ----------------
__global__ __launch_bounds__(256) void cvt3(const float* __restrict__ s0, const float* __restrict__ s1,
                                            const float* __restrict__ s2,
                                            u16* __restrict__ d0, u16* __restrict__ d1, u16* __restrict__ d2){
  const float* s = (blockIdx.y == 0) ? s0 : (blockIdx.y == 1) ? s1 : s2;
  u16*         d = (blockIdx.y == 0) ? d0 : (blockIdx.y == 1) ? d1 : d2;
  int i = blockIdx.x*256 + threadIdx.x;
  float4 v = ((const float4*)s)[i];
  ushort4 o = { f2bf(v.x), f2bf(v.y), f2bf(v.z), f2bf(v.w) };
  ((ushort4*)d)[i] = o;
}
__global__ __launch_bounds__(256) void cvt4(const float* __restrict__ s0, const float* __restrict__ s1,
                                            const float* __restrict__ s2, const float* __restrict__ s3,
                                            u16* __restrict__ d0, u16* __restrict__ d1,
                                            u16* __restrict__ d2, u16* __restrict__ d3){
  const float* s = (blockIdx.y == 0) ? s0 : (blockIdx.y == 1) ? s1 : (blockIdx.y == 2) ? s2 : s3;
  u16*         d = (blockIdx.y == 0) ? d0 : (blockIdx.y == 1) ? d1 : (blockIdx.y == 2) ? d2 : d3;
  int i = blockIdx.x*256 + threadIdx.x;
  float4 v = ((const float4*)s)[i];
  ushort4 o = { f2bf(v.x), f2bf(v.y), f2bf(v.z), f2bf(v.w) };
  ((ushort4*)d)[i] = o;
}

// ---------------- RoPE in place on bf16 tensor [m][h][d], inline sincos ----------------
__global__ __launch_bounds__(256) void rope_kernel(u32* __restrict__ x, const int* __restrict__ pos){
  int p = blockIdx.x*256 + threadIdx.x;       // exact grid: MR*DMn/2 pairs
  int s = (p >> 9) & (SEQn - 1);
  int k = p & 31;
  float inv = powf(10000.0f, -(float)k * (1.0f/32.0f));   // theta^(-2k/64)
  float a = (float)pos[s] * inv;
  float sn, cs;
  sincosf(a, &sn, &cs);
  u32 u = x[p];
  float xe = bf2f(u & 0xffffu);
  float xo = bf2f(u >> 16);
  float re = xe*cs - xo*sn;
  float ro = xe*sn + xo*cs;
  x[p] = (u32)f2bf(re) | ((u32)f2bf(ro) << 16);
}

// ---------------- bf16 MFMA GEMM, m97 structure: C = A * B^T ----------------
// 128x128 tile, BK=64, global_load_lds(16B) with PRE-SWIZZLED global source
// (rule 21: linear LDS dest, src and read share the chunk^=(row&7) involution).
template<typename CT>
__device__ __forceinline__ void gemm_bb_body(const u16* __restrict__ A, const u16* __restrict__ B,
                                             CT* __restrict__ C, int bx, int by){
  __shared__ u16 As[128*64];
  __shared__ u16 Bs[128*64];
  const int tid = threadIdx.x, lane = tid & 63, w = tid >> 6;
  const int m0 = by*128, n0 = bx*128;
  const int wr = (w >> 1)*64, wc = (w & 1)*64;
  const int l15 = lane & 15, lg = lane >> 4;
  f32x4 acc[4][4];
#pragma unroll
  for (int i = 0; i < 4; i++)
#pragma unroll
    for (int j = 0; j < 4; j++) acc[i][j] = (f32x4){0.f,0.f,0.f,0.f};

  for (int kt = 0; kt < DMn; kt += 64){
    __syncthreads();                      // prev reads done before overwrite
#pragma unroll
    for (int i = 0; i < 4; i++){
      const int c = i*256 + tid, row = c >> 3, cc = c & 7;
      gload16(A + (size_t)(m0 + row)*DMn + kt + ((cc ^ (row&7))<<3), &As[(size_t)c<<3]);
    }
#pragma unroll
    for (int i = 0; i < 4; i++){
      const int c = i*256 + tid, row = c >> 3, cc = c & 7;
      gload16(B + (size_t)(n0 + row)*DMn + kt + ((cc ^ (row&7))<<3), &Bs[(size_t)c<<3]);
    }
    __syncthreads();                      // drains vmcnt(0) + barrier

#pragma unroll
    for (int kk = 0; kk < 2; kk++){
      bf16x8 af[4], bfr[4];
      const int ch = kk*4 + lg;
#pragma unroll
      for (int i = 0; i < 4; i++){
        const int row = wr + i*16 + l15;
        af[i] = *(const bf16x8*)&As[row*64 + ((ch ^ (row&7))<<3)];
      }
#pragma unroll
      for (int j = 0; j < 4; j++){
        const int col = wc + j*16 + l15;
        bfr[j] = *(const bf16x8*)&Bs[col*64 + ((ch ^ (col&7))<<3)];
      }
#pragma unroll
      for (int i = 0; i < 4; i++)
#pragma unroll
        for (int j = 0; j < 4; j++)
          acc[i][j] = __builtin_amdgcn_mfma_f32_16x16x32_bf16(af[i], bfr[j], acc[i][j], 0, 0, 0);
    }
  }

#pragma unroll
  for (int i = 0; i < 4; i++)
#pragma unroll
    for (int j = 0; j < 4; j++)
#pragma unroll
      for (int r = 0; r < 4; r++){
        const int row = m0 + wr + i*16 + lg*4 + r;
        const int col = n0 + wc + j*16 + l15;
        if constexpr (sizeof(CT) == 2) C[(size_t)row*DMn + col] = f2bf(acc[i][j][r]);
        else                           C[(size_t)row*DMn + col] = acc[i][j][r];
      }
}

__global__ __launch_bounds__(256) void gemm_qkv_bb(const u16* A0, const u16* A1, const u16* A2,
                                                   const u16* W0, const u16* W1, const u16* W2,
                                                   u16* C0, u16* C1, u16* C2){
  const int z = blockIdx.z;
  const u16* A = (z == 0) ? A0 : (z == 1) ? A1 : A2;
  const u16* W = (z == 0) ? W0 : (z == 1) ? W1 : W2;
  u16*       C = (z == 0) ? C0 : (z == 1) ? C1 : C2;
  gemm_bb_body<u16>(A, W, C, blockIdx.x, blockIdx.y);
}
__global__ __launch_bounds__(256) void gemm_out_bb(const u16* A, const u16* W, float* C){
  gemm_bb_body<float>(A, W, C, blockIdx.x, blockIdx.y);
}

// ---------------- FALLBACK f32-input GEMM (round-8, validated) ----------------
template<typename AT, typename CT>
__device__ __forceinline__ void gemm_body(const AT* __restrict__ A, const float* __restrict__ W,
                                          CT* __restrict__ C, int bx, int by){
  __shared__ u16 As[128*64];
  __shared__ u16 Bs[128*64];
  const int tid = threadIdx.x, lane = tid & 63, w = tid >> 6;
  const int m0 = by*128, n0 = bx*128;
  const int wr = (w >> 1)*64, wc = (w & 1)*64;
  const int l15 = lane & 15, lg = lane >> 4;
  f32x4 acc[4][4];
#pragma unroll
  for (int i = 0; i < 4; i++)
#pragma unroll
    for (int j = 0; j < 4; j++) acc[i][j] = (f32x4){0.f,0.f,0.f,0.f};

  for (int kt = 0; kt < DMn; kt += 64){
    float4 wv[8];
#pragma unroll
    for (int it = 0; it < 8; it++){
      const int f = it*256 + tid, row = f >> 4, c4 = f & 15;
      wv[it] = *(const float4*)(W + (size_t)(n0 + row)*DMn + kt + c4*4);
    }
    if constexpr (sizeof(AT) == 4){
      float4 av[8];
#pragma unroll
      for (int it = 0; it < 8; it++){
        const int f = it*256 + tid, row = f >> 4, c4 = f & 15;
        av[it] = *(const float4*)((const float*)A + (size_t)(m0 + row)*DMn + kt + c4*4);
      }
      __syncthreads();
#pragma unroll
      for (int it = 0; it < 8; it++){
        const int f = it*256 + tid, row = f >> 4, c4 = f & 15;
        ushort4 o = { f2bf(av[it].x), f2bf(av[it].y), f2bf(av[it].z), f2bf(av[it].w) };
        *(ushort4*)&As[row*64 + (((c4>>1) ^ (row&7))<<3) + ((c4&1)<<2)] = o;
      }
    } else {
      uint4 av4[4];
#pragma unroll
      for (int it = 0; it < 4; it++){
        const int f = it*256 + tid, row = f >> 3, ch = f & 7;
        av4[it] = *(const uint4*)((const u16*)A + (size_t)(m0 + row)*DMn + kt + ch*8);
      }
      __syncthreads();
#pragma unroll
      for (int it = 0; it < 4; it++){
        const int f = it*256 + tid, row = f >> 3, ch = f & 7;
        *(uint4*)&As[row*64 + ((ch ^ (row&7))<<3)] = av4[it];
      }
    }
#pragma unroll
    for (int it = 0; it < 8; it++){
      const int f = it*256 + tid, row = f >> 4, c4 = f & 15;
      ushort4 o = { f2bf(wv[it].x), f2bf(wv[it].y), f2bf(wv[it].z), f2bf(wv[it].w) };
      *(ushort4*)&Bs[row*64 + (((c4>>1) ^ (row&7))<<3) + ((c4&1)<<2)] = o;
    }
    __syncthreads();

#pragma unroll
    for (int kk = 0; kk < 2; kk++){
      bf16x8 af[4], bfr[4];
      const int ch = kk*4 + lg;
#pragma unroll
      for (int i = 0; i < 4; i++){
        const int row = wr + i*16 + l15;
        af[i] = *(const bf16x8*)&As[row*64 + ((ch ^ (row&7))<<3)];
      }
#pragma unroll
      for (int j = 0; j < 4; j++){
        const int col = wc + j*16 + l15;
        bfr[j] = *(const bf16x8*)&Bs[col*64 + ((ch ^ (col&7))<<3)];
      }
#pragma unroll
      for (int i = 0; i < 4; i++)
#pragma unroll
        for (int j = 0; j < 4; j++)
          acc[i][j] = __builtin_amdgcn_mfma_f32_16x16x32_bf16(af[i], bfr[j], acc[i][j], 0, 0, 0);
    }
    __syncthreads();
  }

#pragma unroll
  for (int i = 0; i < 4; i++)
#pragma unroll
    for (int j = 0; j < 4; j++)
#pragma unroll
      for (int r = 0; r < 4; r++){
        const int row = m0 + wr + i*16 + lg*4 + r;
        const int col = n0 + wc + j*16 + l15;
        if constexpr (sizeof(CT) == 2) C[(size_t)row*DMn + col] = f2bf(acc[i][j][r]);
        else                           C[(size_t)row*DMn + col] = acc[i][j][r];
      }
}

__global__ __launch_bounds__(256) void gemm_qkv(const float* A0, const float* A1, const float* A2,
                                                const float* W0, const float* W1, const float* W2,
                                                u16* C0, u16* C1, u16* C2){
  const int z = blockIdx.z;
  const float* A = (z == 0) ? A0 : (z == 1) ? A1 : A2;
  const float* W = (z == 0) ? W0 : (z == 1) ? W1 : W2;
  u16*         C = (z == 0) ? C0 : (z == 1) ? C1 : C2;
  gemm_body<float, u16>(A, W, C, blockIdx.x, blockIdx.y);
}
__global__ __launch_bounds__(256) void gemm_out(const u16* A, const float* W, float* C){
  gemm_body<u16, float>(A, W, C, blockIdx.x, blockIdx.y);
}

// ---------------- MFMA causal flash attention (round-8 core + T1 XCD swizzle) ----------------
struct StageRegs { uint4 k0, k1, v0, v1; };

__device__ __forceinline__ StageRegs stage_load(const u16* __restrict__ xk, const u16* __restrict__ xv,
                                                size_t bhbase, int kt, int tid){
  StageRegs r;
  const int row = tid >> 2, c2 = (tid & 3)*2;
  const u16* ks = xk + bhbase + (size_t)(kt + row)*DMn + c2*8;
  r.k0 = *(const uint4*)ks;
  r.k1 = *(const uint4*)(ks + 8);
  const int k = tid & 63, dbase = (tid >> 6)*16;
  const u16* vs = xv + bhbase + (size_t)(kt + k)*DMn + dbase;
  r.v0 = *(const uint4*)vs;
  r.v1 = *(const uint4*)(vs + 8);
  return r;
}

__device__ __forceinline__ void stage_write(u16* __restrict__ Kl, u16* __restrict__ Vt,
                                            const StageRegs& r, int tid){
  const int row = tid >> 2, c2 = (tid & 3)*2;
  *(uint4*)&Kl[row*64 + (( c2    ^ (row&7))<<3)] = r.k0;
  *(uint4*)&Kl[row*64 + (((c2+1) ^ (row&7))<<3)] = r.k1;
  const int k = tid & 63, dbase = (tid >> 6)*16;
  u16 tmp[16];
  *(uint4*)&tmp[0] = r.v0; *(uint4*)&tmp[8] = r.v1;
#pragma unroll
  for (int j = 0; j < 16; j++){
    const int d = dbase + j;
    Vt[d*64 + (((k>>3) ^ (d&7))<<3) + (k&7)] = tmp[j];
  }
}

__device__ __forceinline__ void attn_phase(const u16* __restrict__ xq, const u16* __restrict__ xk,
                                           const u16* __restrict__ xv, u16* __restrict__ xo,
                                           u16* __restrict__ Kl0, u16* __restrict__ Kl1,
                                           u16* __restrict__ Vt0, u16* __restrict__ Vt1,
                                           u16* __restrict__ Plw, size_t bhbase, int qt, int tid){
  const int lane = tid & 63, w = tid >> 6;
  const int l15 = lane & 15, lg = lane >> 4;
  const int qw = qt*64 + w*16;

  const u16* qptr = xq + bhbase + (size_t)(qw + l15)*DMn + lg*8;
  const bf16x8 qf0 = *(const bf16x8*)(qptr);
  const bf16x8 qf1 = *(const bf16x8*)(qptr + 32);

  float mrow[4], lrow[4];
  f32x4 accO[4];
#pragma unroll
  for (int r = 0; r < 4; r++){ mrow[r] = -3e38f; lrow[r] = 0.f; }
#pragma unroll
  for (int df = 0; df < 4; df++) accO[df] = (f32x4){0.f,0.f,0.f,0.f};

  StageRegs sr = stage_load(xk, xv, bhbase, 0, tid);
  stage_write(Kl0, Vt0, sr, tid);
  __syncthreads();

  for (int t = 0; t <= qt; t++){
    const int kt = t*64;
    u16* Kc = (t & 1) ? Kl1 : Kl0;
    u16* Vc = (t & 1) ? Vt1 : Vt0;
    if (t < qt) sr = stage_load(xk, xv, bhbase, kt + 64, tid);   // overlap HBM with compute

    f32x4 sc[4];
    __builtin_amdgcn_s_setprio(1);
#pragma unroll
    for (int f = 0; f < 4; f++){
      const int n = 16*f + l15;
      bf16x8 kb0 = *(const bf16x8*)&Kc[n*64 + (( lg    ^ (n&7))<<3)];
      bf16x8 kb1 = *(const bf16x8*)&Kc[n*64 + (((lg+4) ^ (n&7))<<3)];
      f32x4 z = (f32x4){0.f,0.f,0.f,0.f};
      z = __builtin_amdgcn_mfma_f32_16x16x32_bf16(qf0, kb0, z, 0, 0, 0);
      z = __builtin_amdgcn_mfma_f32_16x16x32_bf16(qf1, kb1, z, 0, 0, 0);
      sc[f] = z;
    }
    __builtin_amdgcn_s_setprio(0);

    const bool needmask = (kt + 63 > qw);
    float mx[4];
#pragma unroll
    for (int r = 0; r < 4; r++){
      float v0 = sc[0][r]*0.125f, v1 = sc[1][r]*0.125f;
      float v2 = sc[2][r]*0.125f, v3 = sc[3][r]*0.125f;
      if (needmask){
        const int qg = qw + lg*4 + r;
        if (kt +      l15 > qg) v0 = -3e38f;
        if (kt + 16 + l15 > qg) v1 = -3e38f;
        if (kt + 32 + l15 > qg) v2 = -3e38f;
        if (kt + 48 + l15 > qg) v3 = -3e38f;
      }
      sc[0][r]=v0; sc[1][r]=v1; sc[2][r]=v2; sc[3][r]=v3;
      mx[r] = fmaxf(fmaxf(v0,v1), fmaxf(v2,v3));
    }
#pragma unroll
    for (int r = 0; r < 4; r++){
      float v = mx[r];
      v = fmaxf(v, __shfl_xor(v, 1));
      v = fmaxf(v, __shfl_xor(v, 2));
      v = fmaxf(v, __shfl_xor(v, 4));
      v = fmaxf(v, __shfl_xor(v, 8));
      mx[r] = v;
    }
#pragma unroll
    for (int r = 0; r < 4; r++){
      const float mn = fmaxf(mrow[r], mx[r]);
      const float corr = __expf(mrow[r] - mn);
      mrow[r] = mn;
      const float p0 = __expf(sc[0][r]-mn), p1 = __expf(sc[1][r]-mn);
      const float p2 = __expf(sc[2][r]-mn), p3 = __expf(sc[3][r]-mn);
      const int q = lg*4 + r, qb = q*64, qx = q&7;
      const int k0 = l15, k1 = 16+l15, k2 = 32+l15, k3 = 48+l15;
      Plw[qb + (((k0>>3) ^ qx)<<3) + (k0&7)] = f2bf(p0);
      Plw[qb + (((k1>>3) ^ qx)<<3) + (k1&7)] = f2bf(p1);
      Plw[qb + (((k2>>3) ^ qx)<<3) + (k2&7)] = f2bf(p2);
      Plw[qb + (((k3>>3) ^ qx)<<3) + (k3&7)] = f2bf(p3);
      float s = ((p0+p1)+(p2+p3));
      s += __shfl_xor(s, 1);
      s += __shfl_xor(s, 2);
      s += __shfl_xor(s, 4);
      s += __shfl_xor(s, 8);
      lrow[r] = lrow[r]*corr + s;
      accO[0][r] *= corr; accO[1][r] *= corr; accO[2][r] *= corr; accO[3][r] *= corr;
    }
    __builtin_amdgcn_s_setprio(1);
#pragma unroll
    for (int ks = 0; ks < 2; ks++){
      bf16x8 pa = *(const bf16x8*)&Plw[ l15*64 + (((4*ks + lg) ^ (l15&7))<<3) ];
#pragma unroll
      for (int df = 0; df < 4; df++){
        const int d = 16*df + l15;
        bf16x8 vb = *(const bf16x8*)&Vc[ d*64 + (((4*ks + lg) ^ (d&7))<<3) ];
        accO[df] = __builtin_amdgcn_mfma_f32_16x16x32_bf16(pa, vb, accO[df], 0, 0, 0);
      }
    }
    __builtin_amdgcn_s_setprio(0);

    if (t < qt) stage_write((t & 1) ? Kl0 : Kl1, (t & 1) ? Vt0 : Vt1, sr, tid);
    __syncthreads();
  }

#pragma unroll
  for (int r = 0; r < 4; r++){
    const float inv = 1.0f / lrow[r];
    const int qg = qw + lg*4 + r;
    u16* dst = xo + bhbase + (size_t)qg*DMn;
#pragma unroll
    for (int df = 0; df < 4; df++)
      dst[16*df + l15] = f2bf(accO[df][r] * inv);
  }
}

// 1D grid of 512; orig = (bh&7) + 8*qx + 128*(bh>>3) keeps all 16 q-blocks of a
// head on one XCD (xcd = orig%8 heuristic) -> K/V stream L2-resident (4 heads = 2MB/XCD).
__global__ __launch_bounds__(256) void attn_mfma(const u16* __restrict__ xq, const u16* __restrict__ xk,
                                                 const u16* __restrict__ xv, u16* __restrict__ xo){
  __shared__ u16 Kl[2][64*64];
  __shared__ u16 Vt[2][64*64];
  __shared__ u16 Pl[4][16*64];
  const int tid = threadIdx.x;
  const int orig = blockIdx.x;
  const int xcd = orig & 7, qx = (orig >> 3) & 15, bhhi = orig >> 7;
  const int bh = (bhhi << 3) | xcd;
  const int b = bh >> 4, h = bh & 15;
  const size_t bhbase = (size_t)b*SEQn*DMn + (size_t)h*DKn;
  u16* Plw = &Pl[tid >> 6][0];

  attn_phase(xq, xk, xv, xo, &Kl[0][0], &Kl[1][0], &Vt[0][0], &Vt[1][0], Plw, bhbase, qx,      tid);
  attn_phase(xq, xk, xv, xo, &Kl[0][0], &Kl[1][0], &Vt[0][0], &Vt[1][0], Plw, bhbase, 31 - qx, tid);
}

extern "C" void kernel_launch(void* const* d_in, const int* in_sizes, int n_in,
                              void* d_out, int out_size, void* d_ws, size_t ws_size,
                              hipStream_t stream){
  (void)in_sizes; (void)n_in;
  const float* Q  = (const float*)d_in[0];
  const float* K  = (const float*)d_in[1];
  const float* V  = (const float*)d_in[2];
  const int*  pos = (const int*)  d_in[3];
  const float* wq = (const float*)d_in[4];
  const float* wk = (const float*)d_in[5];
  const float* wv = (const float*)d_in[6];
  const float* wo = (const float*)d_in[7];

  const size_t SZ  = (size_t)MR*DMn;         // 4,194,304 elements
  const size_t TB  = SZ*2;                   // 8 MB per bf16 tensor
  const size_t WSZ = (size_t)DMn*DMn;        // weight elements
  const size_t WB  = WSZ*2;                  // 2 MB per bf16 weight

  if (ws_size >= 6*TB + 4*WB){
    // ---- fast path: pre-converted bf16 + global_load_lds GEMMs ----
    char* w = (char*)d_ws;
    u16* bQ  = (u16*)(w);                    // later reused as xo
    u16* bK  = (u16*)(w + TB);
    u16* bV  = (u16*)(w + 2*TB);
    u16* bwq = (u16*)(w + 3*TB);
    u16* bwk = (u16*)(w + 3*TB + WB);
    u16* bwv = (u16*)(w + 3*TB + 2*WB);
    u16* bwo = (u16*)(w + 3*TB + 3*WB);
    u16* xq  = (u16*)(w + 3*TB + 4*WB);
    u16* xk  = (u16*)(w + 4*TB + 4*WB);
    u16* xv  = (u16*)(w + 5*TB + 4*WB);
    u16* xo  = bQ;                           // bQ dead after gemm_qkv_bb

    dim3 c3((int)(SZ/4/256), 3);
    cvt3<<<c3, 256, 0, stream>>>(Q, K, V, bQ, bK, bV);
    dim3 c4g((int)(WSZ/4/256), 4);
    cvt4<<<c4g, 256, 0, stream>>>(wq, wk, wv, wo, bwq, bwk, bwv, bwo);

    dim3 gg(DMn/128, MR/128, 3);
    gemm_qkv_bb<<<gg, 256, 0, stream>>>(bQ, bK, bV, bwq, bwk, bwv, xq, xk, xv);

    rope_kernel<<<(int)(SZ/2/256), 256, 0, stream>>>((u32*)xq, pos);
    rope_kernel<<<(int)(SZ/2/256), 256, 0, stream>>>((u32*)xk, pos);

    attn_mfma<<<512, 256, 0, stream>>>(xq, xk, xv, xo);

    dim3 go(DMn/128, MR/128);
    gemm_out_bb<<<go, 256, 0, stream>>>(xo, bwo, (float*)d_out);
  } else if (ws_size >= 4*TB){
    // ---- fallback: round-8 validated path ----
    char* w = (char*)d_ws;
    u16* xq = (u16*)(w);
    u16* xk = (u16*)(w + TB);
    u16* xv = (u16*)(w + 2*TB);
    u16* xo = (u16*)(w + 3*TB);

    dim3 gg(DMn/128, MR/128, 3);
    gemm_qkv<<<gg, 256, 0, stream>>>(Q, K, V, wq, wk, wv, xq, xk, xv);
    rope_kernel<<<(int)(SZ/2/256), 256, 0, stream>>>((u32*)xq, pos);
    rope_kernel<<<(int)(SZ/2/256), 256, 0, stream>>>((u32*)xk, pos);
    attn_mfma<<<512, 256, 0, stream>>>(xq, xk, xv, xo);
    dim3 go(DMn/128, MR/128);
    gemm_out<<<go, 256, 0, stream>>>(xo, wo, (float*)d_out);
  } else {
    hipMemsetAsync(d_out, 0x42, (size_t)out_size*4, stream);
  }
}

// Round 10
// 172.646 us; speedup vs baseline: 31.4424x; 1.0227x over previous
//
#include <hip/hip_runtime.h>

typedef unsigned short u16;
typedef unsigned int u32;
using bf16x8 = __attribute__((ext_vector_type(8))) __bf16;
using u16x8  = __attribute__((ext_vector_type(8))) u16;
using f32x4  = __attribute__((ext_vector_type(4))) float;

#define SEQn   2048
#define DMn    1024
#define NHn    16
#define DKn    64
#define BATCHn 2
#define MR     (BATCHn*SEQn)   // 4096 rows

// score scale folded into log2 domain: 1/sqrt(64) * log2(e)
#define SSCALE 0.18033688f
#define DEFER_THR 11.5f        // 8 nats in log2 units

__device__ __forceinline__ u16 f2bf(float f){
  u32 u = __builtin_bit_cast(u32, f);
  u32 r = (u + 0x7FFFu + ((u >> 16) & 1u)) >> 16;   // RNE
  return (u16)r;
}
__device__ __forceinline__ float bf2f(u32 b){ return __builtin_bit_cast(float, b << 16); }

// async global->LDS, 16B per lane (linear dest = wave base + lane*16)
__device__ __forceinline__ void gload16(const void* g, void* l){
  __builtin_amdgcn_global_load_lds((const __attribute__((address_space(1))) unsigned int*)g,
                                   (__attribute__((address_space(3))) unsigned int*)l, 16, 0, 0);
}

// ---------------- f32 -> bf16 converts (vectorized) ----------------
__global__ __launch_bounds__(256) void cvt3(const float* __restrict__ s0, const float* __restrict__ s1,
                                            const float* __restrict__ s2,
                                            u16* __restrict__ d0, u16* __restrict__ d1, u16* __restrict__ d2){
  const float* s = (blockIdx.y == 0) ? s0 : (blockIdx.y == 1) ? s1 : s2;
  u16*         d = (blockIdx.y == 0) ? d0 : (blockIdx.y == 1) ? d1 : d2;
  int i = blockIdx.x*256 + threadIdx.x;
  float4 v = ((const float4*)s)[i];
  ushort4 o = { f2bf(v.x), f2bf(v.y), f2bf(v.z), f2bf(v.w) };
  ((ushort4*)d)[i] = o;
}
__global__ __launch_bounds__(256) void cvt4(const float* __restrict__ s0, const float* __restrict__ s1,
                                            const float* __restrict__ s2, const float* __restrict__ s3,
                                            u16* __restrict__ d0, u16* __restrict__ d1,
                                            u16* __restrict__ d2, u16* __restrict__ d3){
  const float* s = (blockIdx.y == 0) ? s0 : (blockIdx.y == 1) ? s1 : (blockIdx.y == 2) ? s2 : s3;
  u16*         d = (blockIdx.y == 0) ? d0 : (blockIdx.y == 1) ? d1 : (blockIdx.y == 2) ? d2 : d3;
  int i = blockIdx.x*256 + threadIdx.x;
  float4 v = ((const float4*)s)[i];
  ushort4 o = { f2bf(v.x), f2bf(v.y), f2bf(v.z), f2bf(v.w) };
  ((ushort4*)d)[i] = o;
}

// ---------------- RoPE in place on bf16 tensors [m][h][d] (xq and xk in one launch) ----------------
__global__ __launch_bounds__(256) void rope2_kernel(u32* __restrict__ xq, u32* __restrict__ xk,
                                                    const int* __restrict__ pos){
  u32* x = blockIdx.y ? xk : xq;
  int p = blockIdx.x*256 + threadIdx.x;       // exact grid.x: MR*DMn/2 pairs
  int s = (p >> 9) & (SEQn - 1);
  int k = p & 31;
  float inv = powf(10000.0f, -(float)k * (1.0f/32.0f));   // theta^(-2k/64)
  float a = (float)pos[s] * inv;
  float sn, cs;
  sincosf(a, &sn, &cs);
  u32 u = x[p];
  float xe = bf2f(u & 0xffffu);
  float xo = bf2f(u >> 16);
  float re = xe*cs - xo*sn;
  float ro = xe*sn + xo*cs;
  x[p] = (u32)f2bf(re) | ((u32)f2bf(ro) << 16);
}

// ---------------- bf16 MFMA GEMM, m97 structure: C = A * B^T ----------------
// 128x128 tile, BK=64, global_load_lds(16B) with PRE-SWIZZLED global source
// (rule 21: linear LDS dest, src and read share the chunk^=(row&7) involution).
template<typename CT>
__device__ __forceinline__ void gemm_bb_body(const u16* __restrict__ A, const u16* __restrict__ B,
                                             CT* __restrict__ C, int bx, int by){
  __shared__ u16 As[128*64];
  __shared__ u16 Bs[128*64];
  const int tid = threadIdx.x, lane = tid & 63, w = tid >> 6;
  const int m0 = by*128, n0 = bx*128;
  const int wr = (w >> 1)*64, wc = (w & 1)*64;
  const int l15 = lane & 15, lg = lane >> 4;
  f32x4 acc[4][4];
#pragma unroll
  for (int i = 0; i < 4; i++)
#pragma unroll
    for (int j = 0; j < 4; j++) acc[i][j] = (f32x4){0.f,0.f,0.f,0.f};

  for (int kt = 0; kt < DMn; kt += 64){
    __syncthreads();                      // prev reads done before overwrite
#pragma unroll
    for (int i = 0; i < 4; i++){
      const int c = i*256 + tid, row = c >> 3, cc = c & 7;
      gload16(A + (size_t)(m0 + row)*DMn + kt + ((cc ^ (row&7))<<3), &As[(size_t)c<<3]);
    }
#pragma unroll
    for (int i = 0; i < 4; i++){
      const int c = i*256 + tid, row = c >> 3, cc = c & 7;
      gload16(B + (size_t)(n0 + row)*DMn + kt + ((cc ^ (row&7))<<3), &Bs[(size_t)c<<3]);
    }
    __syncthreads();                      // drains vmcnt(0) + barrier

#pragma unroll
    for (int kk = 0; kk < 2; kk++){
      bf16x8 af[4], bfr[4];
      const int ch = kk*4 + lg;
#pragma unroll
      for (int i = 0; i < 4; i++){
        const int row = wr + i*16 + l15;
        af[i] = *(const bf16x8*)&As[row*64 + ((ch ^ (row&7))<<3)];
      }
#pragma unroll
      for (int j = 0; j < 4; j++){
        const int col = wc + j*16 + l15;
        bfr[j] = *(const bf16x8*)&Bs[col*64 + ((ch ^ (col&7))<<3)];
      }
#pragma unroll
      for (int i = 0; i < 4; i++)
#pragma unroll
        for (int j = 0; j < 4; j++)
          acc[i][j] = __builtin_amdgcn_mfma_f32_16x16x32_bf16(af[i], bfr[j], acc[i][j], 0, 0, 0);
    }
  }

#pragma unroll
  for (int i = 0; i < 4; i++)
#pragma unroll
    for (int j = 0; j < 4; j++)
#pragma unroll
      for (int r = 0; r < 4; r++){
        const int row = m0 + wr + i*16 + lg*4 + r;
        const int col = n0 + wc + j*16 + l15;
        if constexpr (sizeof(CT) == 2) C[(size_t)row*DMn + col] = f2bf(acc[i][j][r]);
        else                           C[(size_t)row*DMn + col] = acc[i][j][r];
      }
}

__global__ __launch_bounds__(256) void gemm_qkv_bb(const u16* A0, const u16* A1, const u16* A2,
                                                   const u16* W0, const u16* W1, const u16* W2,
                                                   u16* C0, u16* C1, u16* C2){
  const int z = blockIdx.z;
  const u16* A = (z == 0) ? A0 : (z == 1) ? A1 : A2;
  const u16* W = (z == 0) ? W0 : (z == 1) ? W1 : W2;
  u16*       C = (z == 0) ? C0 : (z == 1) ? C1 : C2;
  gemm_bb_body<u16>(A, W, C, blockIdx.x, blockIdx.y);
}
__global__ __launch_bounds__(256) void gemm_out_bb(const u16* A, const u16* W, float* C){
  gemm_bb_body<float>(A, W, C, blockIdx.x, blockIdx.y);
}

// ---------------- FALLBACK f32-input GEMM (round-8, validated) ----------------
template<typename AT, typename CT>
__device__ __forceinline__ void gemm_body(const AT* __restrict__ A, const float* __restrict__ W,
                                          CT* __restrict__ C, int bx, int by){
  __shared__ u16 As[128*64];
  __shared__ u16 Bs[128*64];
  const int tid = threadIdx.x, lane = tid & 63, w = tid >> 6;
  const int m0 = by*128, n0 = bx*128;
  const int wr = (w >> 1)*64, wc = (w & 1)*64;
  const int l15 = lane & 15, lg = lane >> 4;
  f32x4 acc[4][4];
#pragma unroll
  for (int i = 0; i < 4; i++)
#pragma unroll
    for (int j = 0; j < 4; j++) acc[i][j] = (f32x4){0.f,0.f,0.f,0.f};

  for (int kt = 0; kt < DMn; kt += 64){
    float4 wv[8];
#pragma unroll
    for (int it = 0; it < 8; it++){
      const int f = it*256 + tid, row = f >> 4, c4 = f & 15;
      wv[it] = *(const float4*)(W + (size_t)(n0 + row)*DMn + kt + c4*4);
    }
    if constexpr (sizeof(AT) == 4){
      float4 av[8];
#pragma unroll
      for (int it = 0; it < 8; it++){
        const int f = it*256 + tid, row = f >> 4, c4 = f & 15;
        av[it] = *(const float4*)((const float*)A + (size_t)(m0 + row)*DMn + kt + c4*4);
      }
      __syncthreads();
#pragma unroll
      for (int it = 0; it < 8; it++){
        const int f = it*256 + tid, row = f >> 4, c4 = f & 15;
        ushort4 o = { f2bf(av[it].x), f2bf(av[it].y), f2bf(av[it].z), f2bf(av[it].w) };
        *(ushort4*)&As[row*64 + (((c4>>1) ^ (row&7))<<3) + ((c4&1)<<2)] = o;
      }
    } else {
      uint4 av4[4];
#pragma unroll
      for (int it = 0; it < 4; it++){
        const int f = it*256 + tid, row = f >> 3, ch = f & 7;
        av4[it] = *(const uint4*)((const u16*)A + (size_t)(m0 + row)*DMn + kt + ch*8);
      }
      __syncthreads();
#pragma unroll
      for (int it = 0; it < 4; it++){
        const int f = it*256 + tid, row = f >> 3, ch = f & 7;
        *(uint4*)&As[row*64 + ((ch ^ (row&7))<<3)] = av4[it];
      }
    }
#pragma unroll
    for (int it = 0; it < 8; it++){
      const int f = it*256 + tid, row = f >> 4, c4 = f & 15;
      ushort4 o = { f2bf(wv[it].x), f2bf(wv[it].y), f2bf(wv[it].z), f2bf(wv[it].w) };
      *(ushort4*)&Bs[row*64 + (((c4>>1) ^ (row&7))<<3) + ((c4&1)<<2)] = o;
    }
    __syncthreads();

#pragma unroll
    for (int kk = 0; kk < 2; kk++){
      bf16x8 af[4], bfr[4];
      const int ch = kk*4 + lg;
#pragma unroll
      for (int i = 0; i < 4; i++){
        const int row = wr + i*16 + l15;
        af[i] = *(const bf16x8*)&As[row*64 + ((ch ^ (row&7))<<3)];
      }
#pragma unroll
      for (int j = 0; j < 4; j++){
        const int col = wc + j*16 + l15;
        bfr[j] = *(const bf16x8*)&Bs[col*64 + ((ch ^ (col&7))<<3)];
      }
#pragma unroll
      for (int i = 0; i < 4; i++)
#pragma unroll
        for (int j = 0; j < 4; j++)
          acc[i][j] = __builtin_amdgcn_mfma_f32_16x16x32_bf16(af[i], bfr[j], acc[i][j], 0, 0, 0);
    }
    __syncthreads();
  }

#pragma unroll
  for (int i = 0; i < 4; i++)
#pragma unroll
    for (int j = 0; j < 4; j++)
#pragma unroll
      for (int r = 0; r < 4; r++){
        const int row = m0 + wr + i*16 + lg*4 + r;
        const int col = n0 + wc + j*16 + l15;
        if constexpr (sizeof(CT) == 2) C[(size_t)row*DMn + col] = f2bf(acc[i][j][r]);
        else                           C[(size_t)row*DMn + col] = acc[i][j][r];
      }
}

__global__ __launch_bounds__(256) void gemm_qkv(const float* A0, const float* A1, const float* A2,
                                                const float* W0, const float* W1, const float* W2,
                                                u16* C0, u16* C1, u16* C2){
  const int z = blockIdx.z;
  const float* A = (z == 0) ? A0 : (z == 1) ? A1 : A2;
  const float* W = (z == 0) ? W0 : (z == 1) ? W1 : W2;
  u16*         C = (z == 0) ? C0 : (z == 1) ? C1 : C2;
  gemm_body<float, u16>(A, W, C, blockIdx.x, blockIdx.y);
}
__global__ __launch_bounds__(256) void gemm_out(const u16* A, const float* W, float* C){
  gemm_body<u16, float>(A, W, C, blockIdx.x, blockIdx.y);
}

// ---------------- MFMA causal flash attention ----------------
// Round-9 core (paired q-tiles, dbuf staging, T1 XCD swizzle) +
// round-10 softmax cuts: exp2 domain, MFMA row-sum (ones-B trick), T13 defer-max.
struct StageRegs { uint4 k0, k1, v0, v1; };

__device__ __forceinline__ StageRegs stage_load(const u16* __restrict__ xk, const u16* __restrict__ xv,
                                                size_t bhbase, int kt, int tid){
  StageRegs r;
  const int row = tid >> 2, c2 = (tid & 3)*2;
  const u16* ks = xk + bhbase + (size_t)(kt + row)*DMn + c2*8;
  r.k0 = *(const uint4*)ks;
  r.k1 = *(const uint4*)(ks + 8);
  const int k = tid & 63, dbase = (tid >> 6)*16;
  const u16* vs = xv + bhbase + (size_t)(kt + k)*DMn + dbase;
  r.v0 = *(const uint4*)vs;
  r.v1 = *(const uint4*)(vs + 8);
  return r;
}

__device__ __forceinline__ void stage_write(u16* __restrict__ Kl, u16* __restrict__ Vt,
                                            const StageRegs& r, int tid){
  const int row = tid >> 2, c2 = (tid & 3)*2;
  *(uint4*)&Kl[row*64 + (( c2    ^ (row&7))<<3)] = r.k0;
  *(uint4*)&Kl[row*64 + (((c2+1) ^ (row&7))<<3)] = r.k1;
  const int k = tid & 63, dbase = (tid >> 6)*16;
  u16 tmp[16];
  *(uint4*)&tmp[0] = r.v0; *(uint4*)&tmp[8] = r.v1;
#pragma unroll
  for (int j = 0; j < 16; j++){
    const int d = dbase + j;
    Vt[d*64 + (((k>>3) ^ (d&7))<<3) + (k&7)] = tmp[j];
  }
}

__device__ __forceinline__ void attn_phase(const u16* __restrict__ xq, const u16* __restrict__ xk,
                                           const u16* __restrict__ xv, u16* __restrict__ xo,
                                           u16* __restrict__ Kl0, u16* __restrict__ Kl1,
                                           u16* __restrict__ Vt0, u16* __restrict__ Vt1,
                                           u16* __restrict__ Plw, size_t bhbase, int qt, int tid){
  const int lane = tid & 63, w = tid >> 6;
  const int l15 = lane & 15, lg = lane >> 4;
  const int qw = qt*64 + w*16;

  const u16* qptr = xq + bhbase + (size_t)(qw + l15)*DMn + lg*8;
  const bf16x8 qf0 = *(const bf16x8*)(qptr);
  const bf16x8 qf1 = *(const bf16x8*)(qptr + 32);

  const u16x8 ou = {0x3F80,0x3F80,0x3F80,0x3F80,0x3F80,0x3F80,0x3F80,0x3F80};
  const bf16x8 onesf = __builtin_bit_cast(bf16x8, ou);

  float mrow[4], lrow[4];
  f32x4 accO[4];
#pragma unroll
  for (int r = 0; r < 4; r++){ mrow[r] = -3e38f; lrow[r] = 0.f; }
#pragma unroll
  for (int df = 0; df < 4; df++) accO[df] = (f32x4){0.f,0.f,0.f,0.f};

  StageRegs sr = stage_load(xk, xv, bhbase, 0, tid);
  stage_write(Kl0, Vt0, sr, tid);
  __syncthreads();

  for (int t = 0; t <= qt; t++){
    const int kt = t*64;
    u16* Kc = (t & 1) ? Kl1 : Kl0;
    u16* Vc = (t & 1) ? Vt1 : Vt0;
    if (t < qt) sr = stage_load(xk, xv, bhbase, kt + 64, tid);   // overlap HBM with compute

    f32x4 sc[4];
    __builtin_amdgcn_s_setprio(1);
#pragma unroll
    for (int f = 0; f < 4; f++){
      const int n = 16*f + l15;
      bf16x8 kb0 = *(const bf16x8*)&Kc[n*64 + (( lg    ^ (n&7))<<3)];
      bf16x8 kb1 = *(const bf16x8*)&Kc[n*64 + (((lg+4) ^ (n&7))<<3)];
      f32x4 z = (f32x4){0.f,0.f,0.f,0.f};
      z = __builtin_amdgcn_mfma_f32_16x16x32_bf16(qf0, kb0, z, 0, 0, 0);
      z = __builtin_amdgcn_mfma_f32_16x16x32_bf16(qf1, kb1, z, 0, 0, 0);
      sc[f] = z;
    }
    __builtin_amdgcn_s_setprio(0);

    // ---- scale into log2 domain + mask (diagonal tile only) + row-group max ----
    const bool needmask = (kt + 63 > qw);
    float mx[4];
#pragma unroll
    for (int r = 0; r < 4; r++){
      float v0 = sc[0][r]*SSCALE, v1 = sc[1][r]*SSCALE;
      float v2 = sc[2][r]*SSCALE, v3 = sc[3][r]*SSCALE;
      if (needmask){
        const int qg = qw + lg*4 + r;
        if (kt +      l15 > qg) v0 = -3e38f;
        if (kt + 16 + l15 > qg) v1 = -3e38f;
        if (kt + 32 + l15 > qg) v2 = -3e38f;
        if (kt + 48 + l15 > qg) v3 = -3e38f;
      }
      sc[0][r]=v0; sc[1][r]=v1; sc[2][r]=v2; sc[3][r]=v3;
      mx[r] = fmaxf(fmaxf(v0,v1), fmaxf(v2,v3));
    }
#pragma unroll
    for (int r = 0; r < 4; r++){
      float v = mx[r];
      v = fmaxf(v, __shfl_xor(v, 1));
      v = fmaxf(v, __shfl_xor(v, 2));
      v = fmaxf(v, __shfl_xor(v, 4));
      v = fmaxf(v, __shfl_xor(v, 8));
      mx[r] = v;
    }
    // ---- T13 defer-max: rescale only when the running max moved materially ----
    const float dm = fmaxf(fmaxf(mx[0]-mrow[0], mx[1]-mrow[1]),
                           fmaxf(mx[2]-mrow[2], mx[3]-mrow[3]));
    if (!__all(dm <= DEFER_THR)){
#pragma unroll
      for (int r = 0; r < 4; r++){
        const float mn = fmaxf(mrow[r], mx[r]);
        const float corr = exp2f(mrow[r] - mn);
        mrow[r] = mn;
        lrow[r] *= corr;
        accO[0][r] *= corr; accO[1][r] *= corr; accO[2][r] *= corr; accO[3][r] *= corr;
      }
    }
    // ---- P = exp2(S - m) -> per-wave LDS (bf16) ----
#pragma unroll
    for (int r = 0; r < 4; r++){
      const float mn = mrow[r];
      const float p0 = exp2f(sc[0][r]-mn), p1 = exp2f(sc[1][r]-mn);
      const float p2 = exp2f(sc[2][r]-mn), p3 = exp2f(sc[3][r]-mn);
      const int q = lg*4 + r, qb = q*64, qx = q&7;
      const int k0 = l15, k1 = 16+l15, k2 = 32+l15, k3 = 48+l15;
      Plw[qb + (((k0>>3) ^ qx)<<3) + (k0&7)] = f2bf(p0);
      Plw[qb + (((k1>>3) ^ qx)<<3) + (k1&7)] = f2bf(p1);
      Plw[qb + (((k2>>3) ^ qx)<<3) + (k2&7)] = f2bf(p2);
      Plw[qb + (((k3>>3) ^ qx)<<3) + (k3&7)] = f2bf(p3);
    }
    // ---- O += P V; l += P·1 via ones-B MFMA (replaces shuffle row-sum) ----
    f32x4 lsum = (f32x4){0.f,0.f,0.f,0.f};
    __builtin_amdgcn_s_setprio(1);
#pragma unroll
    for (int ks = 0; ks < 2; ks++){
      bf16x8 pa = *(const bf16x8*)&Plw[ l15*64 + (((4*ks + lg) ^ (l15&7))<<3) ];
      lsum = __builtin_amdgcn_mfma_f32_16x16x32_bf16(pa, onesf, lsum, 0, 0, 0);
#pragma unroll
      for (int df = 0; df < 4; df++){
        const int d = 16*df + l15;
        bf16x8 vb = *(const bf16x8*)&Vc[ d*64 + (((4*ks + lg) ^ (d&7))<<3) ];
        accO[df] = __builtin_amdgcn_mfma_f32_16x16x32_bf16(pa, vb, accO[df], 0, 0, 0);
      }
    }
    __builtin_amdgcn_s_setprio(0);
#pragma unroll
    for (int r = 0; r < 4; r++) lrow[r] += lsum[r];

    if (t < qt) stage_write((t & 1) ? Kl0 : Kl1, (t & 1) ? Vt0 : Vt1, sr, tid);
    __syncthreads();
  }

#pragma unroll
  for (int r = 0; r < 4; r++){
    const float inv = 1.0f / lrow[r];
    const int qg = qw + lg*4 + r;
    u16* dst = xo + bhbase + (size_t)qg*DMn;
#pragma unroll
    for (int df = 0; df < 4; df++)
      dst[16*df + l15] = f2bf(accO[df][r] * inv);
  }
}

// 1D grid of 512; orig = (bh&7) + 8*qx + 128*(bh>>3) keeps all 16 q-blocks of a
// head on one XCD (xcd = orig%8 heuristic) -> K/V stream L2-resident.
__global__ __launch_bounds__(256) void attn_mfma(const u16* __restrict__ xq, const u16* __restrict__ xk,
                                                 const u16* __restrict__ xv, u16* __restrict__ xo){
  __shared__ u16 Kl[2][64*64];
  __shared__ u16 Vt[2][64*64];
  __shared__ u16 Pl[4][16*64];
  const int tid = threadIdx.x;
  const int orig = blockIdx.x;
  const int xcd = orig & 7, qx = (orig >> 3) & 15, bhhi = orig >> 7;
  const int bh = (bhhi << 3) | xcd;
  const int b = bh >> 4, h = bh & 15;
  const size_t bhbase = (size_t)b*SEQn*DMn + (size_t)h*DKn;
  u16* Plw = &Pl[tid >> 6][0];

  attn_phase(xq, xk, xv, xo, &Kl[0][0], &Kl[1][0], &Vt[0][0], &Vt[1][0], Plw, bhbase, qx,      tid);
  attn_phase(xq, xk, xv, xo, &Kl[0][0], &Kl[1][0], &Vt[0][0], &Vt[1][0], Plw, bhbase, 31 - qx, tid);
}

extern "C" void kernel_launch(void* const* d_in, const int* in_sizes, int n_in,
                              void* d_out, int out_size, void* d_ws, size_t ws_size,
                              hipStream_t stream){
  (void)in_sizes; (void)n_in;
  const float* Q  = (const float*)d_in[0];
  const float* K  = (const float*)d_in[1];
  const float* V  = (const float*)d_in[2];
  const int*  pos = (const int*)  d_in[3];
  const float* wq = (const float*)d_in[4];
  const float* wk = (const float*)d_in[5];
  const float* wv = (const float*)d_in[6];
  const float* wo = (const float*)d_in[7];

  const size_t SZ  = (size_t)MR*DMn;         // 4,194,304 elements
  const size_t TB  = SZ*2;                   // 8 MB per bf16 tensor
  const size_t WSZ = (size_t)DMn*DMn;        // weight elements
  const size_t WB  = WSZ*2;                  // 2 MB per bf16 weight

  if (ws_size >= 6*TB + 4*WB){
    // ---- fast path: pre-converted bf16 + global_load_lds GEMMs ----
    char* w = (char*)d_ws;
    u16* bQ  = (u16*)(w);                    // later reused as xo
    u16* bK  = (u16*)(w + TB);
    u16* bV  = (u16*)(w + 2*TB);
    u16* bwq = (u16*)(w + 3*TB);
    u16* bwk = (u16*)(w + 3*TB + WB);
    u16* bwv = (u16*)(w + 3*TB + 2*WB);
    u16* bwo = (u16*)(w + 3*TB + 3*WB);
    u16* xq  = (u16*)(w + 3*TB + 4*WB);
    u16* xk  = (u16*)(w + 4*TB + 4*WB);
    u16* xv  = (u16*)(w + 5*TB + 4*WB);
    u16* xo  = bQ;                           // bQ dead after gemm_qkv_bb

    dim3 c3((int)(SZ/4/256), 3);
    cvt3<<<c3, 256, 0, stream>>>(Q, K, V, bQ, bK, bV);
    dim3 c4g((int)(WSZ/4/256), 4);
    cvt4<<<c4g, 256, 0, stream>>>(wq, wk, wv, wo, bwq, bwk, bwv, bwo);

    dim3 gg(DMn/128, MR/128, 3);
    gemm_qkv_bb<<<gg, 256, 0, stream>>>(bQ, bK, bV, bwq, bwk, bwv, xq, xk, xv);

    dim3 rg((int)(SZ/2/256), 2);
    rope2_kernel<<<rg, 256, 0, stream>>>((u32*)xq, (u32*)xk, pos);

    attn_mfma<<<512, 256, 0, stream>>>(xq, xk, xv, xo);

    dim3 go(DMn/128, MR/128);
    gemm_out_bb<<<go, 256, 0, stream>>>(xo, bwo, (float*)d_out);
  } else if (ws_size >= 4*TB){
    // ---- fallback: round-8 validated path ----
    char* w = (char*)d_ws;
    u16* xq = (u16*)(w);
    u16* xk = (u16*)(w + TB);
    u16* xv = (u16*)(w + 2*TB);
    u16* xo = (u16*)(w + 3*TB);

    dim3 gg(DMn/128, MR/128, 3);
    gemm_qkv<<<gg, 256, 0, stream>>>(Q, K, V, wq, wk, wv, xq, xk, xv);
    dim3 rg((int)(SZ/2/256), 2);
    rope2_kernel<<<rg, 256, 0, stream>>>((u32*)xq, (u32*)xk, pos);
    attn_mfma<<<512, 256, 0, stream>>>(xq, xk, xv, xo);
    dim3 go(DMn/128, MR/128);
    gemm_out<<<go, 256, 0, stream>>>(xo, wo, (float*)d_out);
  } else {
    hipMemsetAsync(d_out, 0x42, (size_t)out_size*4, stream);
  }
}